// Round 6
// baseline (678.330 us; speedup 1.0000x reference)
//
#include <hip/hip_runtime.h>
#include <math.h>

// SparseViT forward. Round 6: 128x128-tile MFMA GEMM (4x4 acc/wave) for the big
// GEMMs, gate fused into qkv epilogue, ck/cv merged into one dispatch.
// B=2, N=577, DIM=512, H=8, DH=64, DEPTH=2, MLP=2048, NCLS=1000, nc=145, ns=10

#define NTOK 577
#define DIMD 512
#define NH 8
#define DHD 64
#define NC 145
#define NSB 10
#define KSELD 4
#define SBD 64
#define CBD 16
#define CSD 4
#define SWD 32
#define MLPD 2048
#define NCLSD 1000
#define BATCH 2
#define QKVN 1536    // q|k|v columns (output stride)
#define QKVNP 1664   // padded to 13*128 for 128-tile GEMM (incl gate cols 1536..1599)
#define SFSTRIDE 592
#define SCSTRIDE 160
#define PSTRIDE 832  // 640 token cols + 192 compressed cols

typedef unsigned short ushort;
typedef __attribute__((ext_vector_type(8))) short short8;
typedef __attribute__((ext_vector_type(4))) short short4v;
typedef __attribute__((ext_vector_type(4))) float f32x4;

__device__ __forceinline__ ushort bf16_rne(float f) {
  union { float f; unsigned u; } v; v.f = f;
  unsigned u = v.u;
  unsigned r = (u + 0x7fffu + ((u >> 16) & 1u)) >> 16;
  return (ushort)r;
}
__device__ __forceinline__ float bf16_to_f(ushort s) {
  union { unsigned u; float f; } v; v.u = ((unsigned)s) << 16;
  return v.f;
}
__device__ __forceinline__ int imin(int a, int b) { return a < b ? a : b; }
__device__ __forceinline__ int imax(int a, int b) { return a > b ? a : b; }

// ---------------- patch embed + cls + pos ----------------
__global__ void patch_kernel(const float* __restrict__ img, const float* __restrict__ pw,
                             const float* __restrict__ pb, const float* __restrict__ pos,
                             const float* __restrict__ cls, float* __restrict__ x) {
  int idx = blockIdx.x * 256 + threadIdx.x;
  const int total = BATCH * NTOK * DIMD;
  if (idx >= total) return;
  int d = idx & (DIMD - 1);
  int i = (idx / DIMD) % NTOK;
  int b = idx / (DIMD * NTOK);
  float val;
  if (i == 0) {
    val = cls[d];
  } else {
    int p = i - 1;
    val = pb[d];
#pragma unroll
    for (int c = 0; c < 3; ++c)
      val += img[b * 3 * 576 + c * 576 + p] * pw[c * DIMD + d];
  }
  x[idx] = val + pos[i * DIMD + d];
}

// ---------------- layernorm: writes bf16 and/or fp32 ----------------
__global__ void ln_kernel(const float* __restrict__ x, const float* __restrict__ g,
                          const float* __restrict__ bb, ushort* __restrict__ out_bf,
                          float* __restrict__ out_f, long rstride) {
  int row = blockIdx.x;
  const float* xr = x + (long)row * rstride;
  int t = threadIdx.x;
  float a = xr[t], c = xr[t + 256];
  __shared__ float s1[256], s2[256];
  s1[t] = a + c;
  s2[t] = a * a + c * c;
  __syncthreads();
  for (int off = 128; off > 0; off >>= 1) {
    if (t < off) { s1[t] += s1[t + off]; s2[t] += s2[t + off]; }
    __syncthreads();
  }
  float m = s1[0] * (1.0f / 512.0f);
  float var = s2[0] * (1.0f / 512.0f) - m * m;
  float r = rsqrtf(var + 1e-5f);
  float o0 = (a - m) * r * g[t] + bb[t];
  float o1 = (c - m) * r * g[t + 256] + bb[t + 256];
  if (out_bf) {
    out_bf[(long)row * DIMD + t] = bf16_rne(o0);
    out_bf[(long)row * DIMD + t + 256] = bf16_rne(o1);
  }
  if (out_f) {
    out_f[(long)row * DIMD + t] = o0;
    out_f[(long)row * DIMD + t + 256] = o1;
  }
}

// ---------------- ALL weight transposes for one layer in ONE dispatch ----------------
__global__ void wtrans_all_kernel(const float* __restrict__ Wq, const float* __restrict__ Wk,
                                  const float* __restrict__ Wv, const float* __restrict__ Wg,
                                  const float* __restrict__ Wo, const float* __restrict__ Wkc,
                                  const float* __restrict__ Wvc, const float* __restrict__ w1,
                                  const float* __restrict__ w2,
                                  ushort* __restrict__ wqkv_t, ushort* __restrict__ wo_t,
                                  ushort* __restrict__ w1_t, ushort* __restrict__ w2_t,
                                  ushort* __restrict__ wkc_t, ushort* __restrict__ wvc_t) {
  __shared__ float tile[32][33];
  int t = blockIdx.x;
  const float* W; ushort* Wt; int K, N, bx, by;
  if (t < 768) {
    int which = t >> 8, rr = t & 255;
    W = which == 0 ? Wq : (which == 1 ? Wk : Wv);
    Wt = wqkv_t + which * 512 * 512;
    K = 512; N = 512; bx = rr & 15; by = rr >> 4;
  } else if (t < 1024) {
    int rr = t - 768; W = Wo; Wt = wo_t; K = 512; N = 512; bx = rr & 15; by = rr >> 4;
  } else if (t < 2048) {
    int rr = t - 1024; W = w1; Wt = w1_t; K = 512; N = 2048; bx = rr & 63; by = rr >> 6;
  } else if (t < 3072) {
    int rr = t - 2048; W = w2; Wt = w2_t; K = 2048; N = 512; bx = rr & 15; by = rr >> 4;
  } else if (t < 3104) {
    // gate: into wqkv_t rows 1536..1599 (N=24 real, zero-padded to 64)
    int rr = t - 3072; W = Wg; Wt = wqkv_t + (long)1536 * 512; K = 512; N = 24; bx = rr & 1; by = rr >> 1;
  } else if (t < 3168) {
    int rr = t - 3104; W = Wkc; Wt = wkc_t; K = 1024; N = 64; bx = rr & 1; by = rr >> 1;
  } else {
    int rr = t - 3168; W = Wvc; Wt = wvc_t; K = 1024; N = 64; bx = rr & 1; by = rr >> 1;
  }
  int k0 = by * 32, n0 = bx * 32;
  int tx = threadIdx.x, ty = threadIdx.y;
#pragma unroll
  for (int r = 0; r < 32; r += 8)
    tile[ty + r][tx] = (n0 + tx < N) ? W[(long)(k0 + ty + r) * N + n0 + tx] : 0.f;
  __syncthreads();
#pragma unroll
  for (int r = 0; r < 32; r += 8)
    Wt[(long)(n0 + ty + r) * K + k0 + tx] = bf16_rne(tile[tx][ty + r]);
}

// ---------------- 128x128-tile bf16 MFMA GEMM, 4x4 acc per wave ----------------
// mode 0: Cf = A@Bt^T (+bias)(+resid)    (fp32 out, stride N)
// mode 1: Cbf = gelu(A@Bt^T + bias)      (bf16 out, stride N)
// mode 2: qkv+gate fused: col<1536 -> Cbf (stride 1536); 1536<=col<1600 -> sigmoid -> gb
__global__ __launch_bounds__(256) void mfma_gemm128(
    const ushort* __restrict__ A, const ushort* __restrict__ Bt,
    const float* __restrict__ bias, const float* __restrict__ resid,
    float* __restrict__ Cf, ushort* __restrict__ Cbf, float* __restrict__ gb,
    int M, int N, int K, int mode) {
  __shared__ short As[128][72];
  __shared__ short Bs[128][72];
  int tid = threadIdx.x;
  int lane = tid & 63, wave = tid >> 6;
  int wm = wave >> 1, wn = wave & 1;
  int rowBase = blockIdx.y * 128, colBase = blockIdx.x * 128;
  int m = lane & 15, kg = lane >> 4;
  int srow = tid >> 1;
  int skc = (tid & 1) * 4;
  f32x4 acc[4][4] = {};
  for (int k0 = 0; k0 < K; k0 += 64) {
    const ushort* aSrc = A + (long)(rowBase + srow) * K + k0 + skc * 8;
    bool aok = (rowBase + srow) < M;
    const ushort* bSrc = Bt + (long)(colBase + srow) * K + k0 + skc * 8;
#pragma unroll
    for (int j = 0; j < 4; ++j) {
      short8 av = {};
      if (aok) av = *(const short8*)(aSrc + j * 8);
      *(short8*)&As[srow][(skc + j) * 8] = av;
      short8 bv = *(const short8*)(bSrc + j * 8);
      *(short8*)&Bs[srow][(skc + j) * 8] = bv;
    }
    __syncthreads();
#pragma unroll
    for (int ks = 0; ks < 2; ++ks) {
      short8 a[4], b[4];
#pragma unroll
      for (int mt = 0; mt < 4; ++mt) a[mt] = *(const short8*)&As[wm * 64 + mt * 16 + m][ks * 32 + kg * 8];
#pragma unroll
      for (int nt = 0; nt < 4; ++nt) b[nt] = *(const short8*)&Bs[wn * 64 + nt * 16 + m][ks * 32 + kg * 8];
#pragma unroll
      for (int mt = 0; mt < 4; ++mt)
#pragma unroll
        for (int nt = 0; nt < 4; ++nt)
          acc[mt][nt] = __builtin_amdgcn_mfma_f32_16x16x32_bf16(a[mt], b[nt], acc[mt][nt], 0, 0, 0);
    }
    __syncthreads();
  }
#pragma unroll
  for (int mt = 0; mt < 4; ++mt)
#pragma unroll
    for (int nt = 0; nt < 4; ++nt) {
      int col = colBase + wn * 64 + nt * 16 + m;
#pragma unroll
      for (int r = 0; r < 4; ++r) {
        int row = rowBase + wm * 64 + mt * 16 + kg * 4 + r;
        if (row >= M) continue;
        float v = acc[mt][nt][r];
        if (mode == 2) {
          if (col < QKVN) Cbf[(long)row * QKVN + col] = bf16_rne(v);
          else if (col < 1600) gb[(long)row * 64 + (col - 1536)] = 1.f / (1.f + __expf(-v));
        } else if (mode == 1) {
          v += bias[col];
          float u = 0.7978845608028654f * (v + 0.044715f * v * v * v);
          v = 0.5f * v * (1.f + tanhf(u));
          Cbf[(long)row * N + col] = bf16_rne(v);
        } else {
          if (bias) v += bias[col];
          if (resid) v += resid[(long)row * N + col];
          Cf[(long)row * N + col] = v;
        }
      }
    }
}

// ---------------- ck/cv: both halves in one dispatch (z selects) ----------------
__global__ __launch_bounds__(256) void ckcv_gemm(
    const ushort* __restrict__ kwm, const ushort* __restrict__ vwm,
    const ushort* __restrict__ wkc_t, const ushort* __restrict__ wvc_t,
    ushort* __restrict__ ckb, ushort* __restrict__ cvb) {
  const ushort* A = blockIdx.z ? vwm : kwm;
  const ushort* Bt = blockIdx.z ? wvc_t : wkc_t;
  ushort* C = blockIdx.z ? cvb : ckb;
  const int M = BATCH * NH * NC, N = 64, K = 1024;
  __shared__ short As[64][72];
  __shared__ short Bs[64][72];
  int tid = threadIdx.x;
  int lane = tid & 63, wave = tid >> 6;
  int wm = wave >> 1, wn = wave & 1;
  int rowBase = blockIdx.y * 64;
  int m = lane & 15, kg = lane >> 4;
  f32x4 acc[2][2] = {};
  for (int k0 = 0; k0 < K; k0 += 64) {
#pragma unroll
    for (int cc = 0; cc < 2; ++cc) {
      int c = tid * 2 + cc;
      int r = c >> 3, kc = c & 7;
      short8 av = {};
      int gr = rowBase + r;
      if (gr < M) av = *(const short8*)(A + (long)gr * K + k0 + kc * 8);
      *(short8*)&As[r][kc * 8] = av;
      short8 bv = *(const short8*)(Bt + (long)r * K + k0 + kc * 8);
      *(short8*)&Bs[r][kc * 8] = bv;
    }
    __syncthreads();
#pragma unroll
    for (int ks = 0; ks < 2; ++ks) {
      short8 a0 = *(const short8*)&As[wm * 32 + m][ks * 32 + kg * 8];
      short8 a1 = *(const short8*)&As[wm * 32 + 16 + m][ks * 32 + kg * 8];
      short8 b0 = *(const short8*)&Bs[wn * 32 + m][ks * 32 + kg * 8];
      short8 b1 = *(const short8*)&Bs[wn * 32 + 16 + m][ks * 32 + kg * 8];
      acc[0][0] = __builtin_amdgcn_mfma_f32_16x16x32_bf16(a0, b0, acc[0][0], 0, 0, 0);
      acc[0][1] = __builtin_amdgcn_mfma_f32_16x16x32_bf16(a0, b1, acc[0][1], 0, 0, 0);
      acc[1][0] = __builtin_amdgcn_mfma_f32_16x16x32_bf16(a1, b0, acc[1][0], 0, 0, 0);
      acc[1][1] = __builtin_amdgcn_mfma_f32_16x16x32_bf16(a1, b1, acc[1][1], 0, 0, 0);
    }
    __syncthreads();
  }
#pragma unroll
  for (int mt = 0; mt < 2; ++mt)
#pragma unroll
    for (int nt = 0; nt < 2; ++nt) {
      int col = wn * 32 + nt * 16 + m;
#pragma unroll
      for (int r = 0; r < 4; ++r) {
        int row = rowBase + wm * 32 + mt * 16 + kg * 4 + r;
        if (row < M) C[(long)row * N + col] = bf16_rne(acc[mt][nt][r]);
      }
    }
}

// ---------------- batched score GEMM: merged dense (x<10) + compressed (x>=10) ----------------
__global__ __launch_bounds__(256) void score_kernel(
    const ushort* __restrict__ qkv_bf, const ushort* __restrict__ ckb,
    ushort* __restrict__ Sf, ushort* __restrict__ Scb, float scale) {
  __shared__ short As[64][72];
  __shared__ short Bs[64][72];
  int z = blockIdx.z;
  int b = z >> 3, h = z & 7;
  int i0 = blockIdx.y * 64;
  int xb = blockIdx.x;
  bool isC = xb >= 10;
  int j0 = (isC ? (xb - 10) : xb) * 64;
  int tid = threadIdx.x;
  int lane = tid & 63, wave = tid >> 6;
  int wm = wave >> 1, wn = wave & 1;
  const ushort* aBase = qkv_bf + (long)b * NTOK * QKVN + h * 64;
  const ushort* bBase = aBase + 512;
  const ushort* cBase = ckb + (long)z * NC * DHD;
#pragma unroll
  for (int rep = 0; rep < 4; ++rep) {
    int row = rep * 16 + (tid >> 4);
    int c4 = tid & 15;
    int gi = i0 + row;
    short4v a16 = {};
    if (gi < NTOK) a16 = *(const short4v*)(aBase + (long)gi * QKVN + c4 * 4);
    *(short4v*)&As[row][c4 * 4] = a16;
    int gj = j0 + row;
    short4v b16 = {};
    if (isC) {
      if (gj < NC) b16 = *(const short4v*)(cBase + (long)gj * DHD + c4 * 4);
    } else {
      if (gj < NTOK) b16 = *(const short4v*)(bBase + (long)gj * QKVN + c4 * 4);
    }
    *(short4v*)&Bs[row][c4 * 4] = b16;
  }
  __syncthreads();
  int m = lane & 15, kg = lane >> 4;
  f32x4 acc[2][2] = {};
#pragma unroll
  for (int ks = 0; ks < 2; ++ks) {
    short8 a0 = *(const short8*)&As[wm * 32 + m][ks * 32 + kg * 8];
    short8 a1 = *(const short8*)&As[wm * 32 + 16 + m][ks * 32 + kg * 8];
    short8 b0 = *(const short8*)&Bs[wn * 32 + m][ks * 32 + kg * 8];
    short8 b1 = *(const short8*)&Bs[wn * 32 + 16 + m][ks * 32 + kg * 8];
    acc[0][0] = __builtin_amdgcn_mfma_f32_16x16x32_bf16(a0, b0, acc[0][0], 0, 0, 0);
    acc[0][1] = __builtin_amdgcn_mfma_f32_16x16x32_bf16(a0, b1, acc[0][1], 0, 0, 0);
    acc[1][0] = __builtin_amdgcn_mfma_f32_16x16x32_bf16(a1, b0, acc[1][0], 0, 0, 0);
    acc[1][1] = __builtin_amdgcn_mfma_f32_16x16x32_bf16(a1, b1, acc[1][1], 0, 0, 0);
  }
  int nvalid = isC ? NC : NTOK;
  int sstride = isC ? SCSTRIDE : SFSTRIDE;
  ushort* Sz = (isC ? Scb : Sf) + (long)z * NTOK * sstride;
#pragma unroll
  for (int mt = 0; mt < 2; ++mt)
#pragma unroll
    for (int nt = 0; nt < 2; ++nt) {
      int col = j0 + wn * 32 + nt * 16 + m;
#pragma unroll
      for (int r = 0; r < 4; ++r) {
        int row = i0 + wm * 32 + mt * 16 + kg * 4 + r;
        if (row < NTOK && col < nvalid)
          Sz[(long)row * sstride + col] = bf16_rne(acc[mt][nt][r] * scale);
      }
    }
}

// ---------------- kw/vw build from bf16 qkv ----------------
__global__ void kwbuild_kernel(const ushort* __restrict__ qkv_bf,
                               const float* __restrict__ kpe, const float* __restrict__ vpe,
                               ushort* __restrict__ kwm, ushort* __restrict__ vwm) {
  int r = blockIdx.x;               // 0..2319
  int j = r % NC;
  int bh = r / NC;
  int h = bh & 7, b = bh >> 3;
  int t = threadIdx.x >> 4;
  int d4 = threadIdx.x & 15;
  int tok = j * CSD + t;
  float k0 = 0.f, k1 = 0.f, k2 = 0.f, k3 = 0.f, v0 = 0.f, v1 = 0.f, v2 = 0.f, v3 = 0.f;
  if (tok < NTOK) {
    const ushort* base = qkv_bf + (long)(b * NTOK + tok) * QKVN + h * DHD + d4 * 4;
    short4v kv = *(const short4v*)(base + 512);
    short4v vv = *(const short4v*)(base + 1024);
    k0 = bf16_to_f((ushort)kv.x); k1 = bf16_to_f((ushort)kv.y);
    k2 = bf16_to_f((ushort)kv.z); k3 = bf16_to_f((ushort)kv.w);
    v0 = bf16_to_f((ushort)vv.x); v1 = bf16_to_f((ushort)vv.y);
    v2 = bf16_to_f((ushort)vv.z); v3 = bf16_to_f((ushort)vv.w);
  }
  float4 kp = *(const float4*)(kpe + t * DHD + d4 * 4);
  float4 vp = *(const float4*)(vpe + t * DHD + d4 * 4);
  short4v ko, vo;
  ko.x = (short)bf16_rne(k0 + kp.x); ko.y = (short)bf16_rne(k1 + kp.y);
  ko.z = (short)bf16_rne(k2 + kp.z); ko.w = (short)bf16_rne(k3 + kp.w);
  vo.x = (short)bf16_rne(v0 + vp.x); vo.y = (short)bf16_rne(v1 + vp.y);
  vo.z = (short)bf16_rne(v2 + vp.z); vo.w = (short)bf16_rne(v3 + vp.w);
  long ob = (long)r * 1024 + t * DHD + d4 * 4;
  *(short4v*)(kwm + ob) = ko;
  *(short4v*)(vwm + ob) = vo;
}

// ---------------- Vext^T build ----------------
__global__ void vtrans_kernel(const ushort* __restrict__ qkv_bf, const ushort* __restrict__ cvb,
                              ushort* __restrict__ Vt) {
  int kt = blockIdx.x;   // 0..12
  int z = blockIdx.y;    // 0..15
  int b = z >> 3, h = z & 7;
  __shared__ short tile[64][72];
  int tid = threadIdx.x;
  int r = tid >> 2, seg = tid & 3;
  short8 a0 = {}, a1 = {};
  if (kt < 10) {
    int tok = kt * 64 + r;
    if (tok < NTOK) {
      const ushort* src = qkv_bf + (long)(b * NTOK + tok) * QKVN + 1024 + h * 64 + seg * 16;
      a0 = *(const short8*)src;
      a1 = *(const short8*)(src + 8);
    }
  } else {
    int cr = (kt - 10) * 64 + r;
    if (cr < NC) {
      const ushort* src = cvb + ((long)z * NC + cr) * DHD + seg * 16;
      a0 = *(const short8*)src;
      a1 = *(const short8*)(src + 8);
    }
  }
  *(short8*)&tile[r][seg * 16] = a0;
  *(short8*)&tile[r][seg * 16 + 8] = a1;
  __syncthreads();
  int d = tid >> 2;
  short8 o0, o1;
#pragma unroll
  for (int q = 0; q < 8; ++q) o0[q] = tile[seg * 16 + q][d];
#pragma unroll
  for (int q = 0; q < 8; ++q) o1[q] = tile[seg * 16 + 8 + q][d];
  ushort* dst = Vt + ((long)z * 64 + d) * PSTRIDE + kt * 64 + seg * 16;
  *(short8*)dst = o0;
  *(short8*)(dst + 8) = o1;
}

// ---------------- prob: softmax + top-k + gates -> dense gated P row ----------------
__global__ __launch_bounds__(256, 4) void prob_kernel(
    const ushort* __restrict__ Sf, const ushort* __restrict__ Scb,
    const float* __restrict__ gb, ushort* __restrict__ P) {
  int qt = blockIdx.x % NC;
  int z = blockIdx.x / NC;
  int h = z & 7, b = z >> 3;
  int tid = threadIdx.x, lane = tid & 63, w = tid >> 6;
  int i0 = qt * 4 + w;
  bool valid = i0 < NTOK;
  int i = imin(i0, NTOK - 1);

  __shared__ float scL[4][192];
  __shared__ float ssL[4][256];
  __shared__ float swL[4][32];
  __shared__ float impL[4][16];
  __shared__ int selL[4][KSELD];
  float* sc = scL[w]; float* ss = ssL[w];
  float* swv = swL[w]; float* imp = impL[w]; int* sel = selL[w];

  const ushort* scRow = Scb + ((long)z * NTOK + i) * SCSTRIDE;
  const ushort* sfRow = Sf + ((long)z * NTOK + i) * SFSTRIDE;

  float e[3], mC = -1e30f;
#pragma unroll
  for (int c = 0; c < 3; ++c) {
    int j = c * 64 + lane;
    float s = bf16_to_f(scRow[imin(j, NC - 1)]);
    s = (j < NC) ? s : -1e30f;
    e[c] = s;
    mC = fmaxf(mC, s);
  }
#pragma unroll
  for (int msk = 1; msk < 64; msk <<= 1) mC = fmaxf(mC, __shfl_xor(mC, msk, 64));
  float sumC = 0.f;
#pragma unroll
  for (int c = 0; c < 3; ++c) {
    float ev = (e[c] > -1e29f) ? __expf(e[c] - mC) : 0.f;
    sc[c * 64 + lane] = ev;
    sumC += ev;
  }
#pragma unroll
  for (int msk = 1; msk < 64; msk <<= 1) sumC += __shfl_xor(sumC, msk, 64);
  __syncthreads();

  if (lane < NSB) {
    int lo = imax(0, 16 * lane - 2), hi = imin(NC - 1, 16 * lane + 13);
    float s = 0.f;
    for (int j = lo; j <= hi; ++j) s += sc[j];
    imp[lane] = s;
  }
  __syncthreads();
  if (lane == 0) {
    unsigned used = 0;
    for (int r = 0; r < KSELD; ++r) {
      int bi = 0; float bv = -1e30f;
      for (int s = 0; s < NSB; ++s)
        if (!((used >> s) & 1u) && imp[s] > bv) { bv = imp[s]; bi = s; }
      used |= 1u << bi;
      sel[r] = bi;
    }
  }
  __syncthreads();

  float es[4], mS = -1e30f;
#pragma unroll
  for (int c = 0; c < 4; ++c) {
    int tok = sel[c] * SBD + lane;
    float s = bf16_to_f(sfRow[imin(tok, NTOK - 1)]);
    s = (tok < NTOK) ? s : -1e30f;
    es[c] = s;
    mS = fmaxf(mS, s);
  }
#pragma unroll
  for (int msk = 1; msk < 64; msk <<= 1) mS = fmaxf(mS, __shfl_xor(mS, msk, 64));
  float sumS = 0.f;
#pragma unroll
  for (int c = 0; c < 4; ++c) {
    float ev = (es[c] > -1e29f) ? __expf(es[c] - mS) : 0.f;
    ss[c * 64 + lane] = ev;
    sumS += ev;
  }
#pragma unroll
  for (int msk = 1; msk < 64; msk <<= 1) sumS += __shfl_xor(sumS, msk, 64);

  float sw_s;
  {
    int pos = i + (lane & 31) - SWD / 2;
    float s = bf16_to_f(sfRow[imin(imax(pos, 0), NTOK - 1)]);
    sw_s = (pos >= 0 && pos < NTOK) ? s : -1e30f;
  }
  float mW = sw_s;
#pragma unroll
  for (int msk = 1; msk < 32; msk <<= 1) mW = fmaxf(mW, __shfl_xor(mW, msk, 64));
  float ew = (sw_s > -1e29f) ? __expf(sw_s - mW) : 0.f;
  float sumW = ew;
#pragma unroll
  for (int msk = 1; msk < 32; msk <<= 1) sumW += __shfl_xor(sumW, msk, 64);
  if (lane < SWD) swv[lane] = ew;
  __syncthreads();

  if (!valid) return;
  const float* gp = gb + (long)(b * NTOK + i) * 64 + h * 3;
  float rC = gp[0] / sumC, rS = gp[1] / sumS, rW = gp[2] / sumW;
  ushort* prow = P + ((long)z * NTOK + i0) * PSTRIDE;
#pragma unroll
  for (int c = 0; c < 10; ++c) {
    int col = c * 64 + lane;
    float val = 0.f;
#pragma unroll
    for (int r = 0; r < 4; ++r)
      if (sel[r] == c) val += rS * ss[r * 64 + lane];
    int t = col - i + 16;
    if (t >= 0 && t < SWD && col < NTOK) val += rW * swv[t];
    prow[col] = bf16_rne(val);
  }
#pragma unroll
  for (int c = 0; c < 3; ++c) {
    int j = c * 64 + lane;
    float val = (j < NC) ? rC * sc[j] : 0.f;
    prow[640 + j] = bf16_rne(val);
  }
}

// ---------------- PV GEMM: comb[b,i,h*64+d] = P[z] @ Vext[z] ----------------
__global__ __launch_bounds__(256) void pv_gemm(const ushort* __restrict__ P,
                                               const ushort* __restrict__ Vt,
                                               ushort* __restrict__ comb) {
  __shared__ short As[64][72];
  __shared__ short Bs[64][72];
  int z = blockIdx.y;
  int b = z >> 3, h = z & 7;
  int rowBase = blockIdx.x * 64;
  int tid = threadIdx.x;
  int lane = tid & 63, wave = tid >> 6;
  int wm = wave >> 1, wn = wave & 1;
  const ushort* Pz = P + (long)z * NTOK * PSTRIDE;
  const ushort* Vz = Vt + (long)z * 64 * PSTRIDE;
  int m = lane & 15, kg = lane >> 4;
  f32x4 acc[2][2] = {};
  for (int k0 = 0; k0 < PSTRIDE; k0 += 64) {
#pragma unroll
    for (int cc = 0; cc < 2; ++cc) {
      int c = tid * 2 + cc;
      int r = c >> 3, kc = c & 7;
      short8 av = {};
      int gr = rowBase + r;
      if (gr < NTOK) av = *(const short8*)(Pz + (long)gr * PSTRIDE + k0 + kc * 8);
      *(short8*)&As[r][kc * 8] = av;
      short8 bv = *(const short8*)(Vz + (long)r * PSTRIDE + k0 + kc * 8);
      *(short8*)&Bs[r][kc * 8] = bv;
    }
    __syncthreads();
#pragma unroll
    for (int ks = 0; ks < 2; ++ks) {
      short8 a0 = *(const short8*)&As[wm * 32 + m][ks * 32 + kg * 8];
      short8 a1 = *(const short8*)&As[wm * 32 + 16 + m][ks * 32 + kg * 8];
      short8 b0 = *(const short8*)&Bs[wn * 32 + m][ks * 32 + kg * 8];
      short8 b1 = *(const short8*)&Bs[wn * 32 + 16 + m][ks * 32 + kg * 8];
      acc[0][0] = __builtin_amdgcn_mfma_f32_16x16x32_bf16(a0, b0, acc[0][0], 0, 0, 0);
      acc[0][1] = __builtin_amdgcn_mfma_f32_16x16x32_bf16(a0, b1, acc[0][1], 0, 0, 0);
      acc[1][0] = __builtin_amdgcn_mfma_f32_16x16x32_bf16(a1, b0, acc[1][0], 0, 0, 0);
      acc[1][1] = __builtin_amdgcn_mfma_f32_16x16x32_bf16(a1, b1, acc[1][1], 0, 0, 0);
    }
    __syncthreads();
  }
#pragma unroll
  for (int mt = 0; mt < 2; ++mt)
#pragma unroll
    for (int nt = 0; nt < 2; ++nt) {
      int col = wn * 32 + nt * 16 + m;
#pragma unroll
      for (int r = 0; r < 4; ++r) {
        int row = rowBase + wm * 32 + mt * 16 + kg * 4 + r;
        if (row < NTOK)
          comb[(long)(b * NTOK + row) * DIMD + h * 64 + col] = bf16_rne(acc[mt][nt][r]);
      }
    }
}

// ---------------- head ----------------
__global__ void head_kernel(const float* __restrict__ hfin, const float* __restrict__ W,
                            const float* __restrict__ bias, float* __restrict__ out) {
  __shared__ float hs[512];
  int bidx = blockIdx.y;
  int t = threadIdx.x;
  hs[t] = hfin[bidx * 512 + t];
  hs[t + 256] = hfin[bidx * 512 + t + 256];
  __syncthreads();
  int col = blockIdx.x * 256 + t;
  if (col < NCLSD) {
    float acc = bias[col];
#pragma unroll 8
    for (int k = 0; k < 512; ++k) acc += hs[k] * W[(long)k * NCLSD + col];
    out[bidx * NCLSD + col] = acc;
  }
}

extern "C" void kernel_launch(void* const* d_in, const int* in_sizes, int n_in,
                              void* d_out, int out_size, void* d_ws, size_t ws_size,
                              hipStream_t stream) {
  const float* img     = (const float*)d_in[0];
  const float* patch_w = (const float*)d_in[1];
  const float* patch_b = (const float*)d_in[2];
  const float* pos_emb = (const float*)d_in[3];
  const float* cls_tok = (const float*)d_in[4];
  const float* ln1_g   = (const float*)d_in[5];
  const float* ln1_b   = (const float*)d_in[6];
  const float* Wq      = (const float*)d_in[7];
  const float* Wk      = (const float*)d_in[8];
  const float* Wv      = (const float*)d_in[9];
  const float* Wg      = (const float*)d_in[10];
  const float* Wo      = (const float*)d_in[11];
  const float* kpe     = (const float*)d_in[12];
  const float* vpe     = (const float*)d_in[13];
  const float* Wkc     = (const float*)d_in[14];
  const float* Wvc     = (const float*)d_in[15];
  const float* ln2_g   = (const float*)d_in[16];
  const float* ln2_b   = (const float*)d_in[17];
  const float* ff_w1   = (const float*)d_in[18];
  const float* ff_b1   = (const float*)d_in[19];
  const float* ff_w2   = (const float*)d_in[20];
  const float* ff_b2   = (const float*)d_in[21];
  const float* hln_g   = (const float*)d_in[22];
  const float* hln_b   = (const float*)d_in[23];
  const float* head_w  = (const float*)d_in[24];
  const float* head_b  = (const float*)d_in[25];
  float* out = (float*)d_out;

  // ---- workspace carve ----
  char* p = (char*)d_ws;
  const long MROW = (long)BATCH * NTOK;            // 1154
  float* x       = (float*)p;  p += MROW * DIMD * 4;
  ushort* qkv_bf = (ushort*)p; p += MROW * QKVN * 2;
  ushort* h_bf   = (ushort*)p; p += MROW * DIMD * 2;
  ushort* comb_bf= (ushort*)p; p += MROW * DIMD * 2;
  float* gb      = (float*)p;  p += MROW * 64 * 4;
  ushort* ckb    = (ushort*)p; p += (long)BATCH * NH * NC * DHD * 2;
  ushort* cvb    = (ushort*)p; p += (long)BATCH * NH * NC * DHD * 2;
  ushort* Vt     = (ushort*)p; p += (long)BATCH * NH * 64 * PSTRIDE * 2;
  ushort* Scb    = (ushort*)p; p += (long)BATCH * NH * NTOK * SCSTRIDE * 2;
  float* hfin    = (float*)p;  p += BATCH * DIMD * 4;
  ushort* wqkv_t = (ushort*)p; p += (long)QKVNP * DIMD * 2;   // 1664 rows (q|k|v|gate|pad)
  ushort* wo_t   = (ushort*)p; p += (long)DIMD * DIMD * 2;
  ushort* w1_t   = (ushort*)p; p += (long)MLPD * DIMD * 2;
  ushort* w2_t   = (ushort*)p; p += (long)DIMD * MLPD * 2;
  ushort* wkc_t  = (ushort*)p; p += (long)64 * 1024 * 2;
  ushort* wvc_t  = (ushort*)p; p += (long)64 * 1024 * 2;
  // region A: kwm+vwm aliased with P (disjoint lifetimes)
  ushort* kwm    = (ushort*)p;
  ushort* vwm    = kwm + (long)BATCH * NH * NC * 1024;
  ushort* P      = kwm;
  p += (long)BATCH * NH * NTOK * PSTRIDE * 2;
  // region B: Sf aliased with ff1_bf (disjoint lifetimes)
  ushort* Sf     = (ushort*)p;
  ushort* ff1_bf = Sf;
  p += (long)BATCH * NH * NTOK * SFSTRIDE * 2;

  const int M = (int)MROW;                  // 1154
  const int MB128 = (M + 127) / 128;        // 10
  const int MCK = BATCH * NH * NC;          // 2320
  const float scale = 0.125f;
  dim3 thrT(32, 8);

  patch_kernel<<<(M * DIMD + 255) / 256, 256, 0, stream>>>(img, patch_w, patch_b, pos_emb, cls_tok, x);

  for (int l = 0; l < 2; ++l) {
    const float* Wq_l  = Wq + (long)l * DIMD * DIMD;
    const float* Wk_l  = Wk + (long)l * DIMD * DIMD;
    const float* Wv_l  = Wv + (long)l * DIMD * DIMD;
    const float* Wg_l  = Wg + (long)l * DIMD * 3 * NH;
    const float* Wo_l  = Wo + (long)l * DIMD * DIMD;
    const float* kpe_l = kpe + (long)l * CBD * DHD;
    const float* vpe_l = vpe + (long)l * CBD * DHD;
    const float* Wkc_l = Wkc + (long)l * CBD * DHD * DHD;
    const float* Wvc_l = Wvc + (long)l * CBD * DHD * DHD;
    const float* w1_l  = ff_w1 + (long)l * DIMD * MLPD;
    const float* b1_l  = ff_b1 + (long)l * MLPD;
    const float* w2_l  = ff_w2 + (long)l * MLPD * DIMD;
    const float* b2_l  = ff_b2 + (long)l * DIMD;

    wtrans_all_kernel<<<3232, thrT, 0, stream>>>(Wq_l, Wk_l, Wv_l, Wg_l, Wo_l, Wkc_l, Wvc_l,
                                                 w1_l, w2_l, wqkv_t, wo_t, w1_t, w2_t,
                                                 wkc_t, wvc_t);
    // h = LN1(x) -> bf16
    ln_kernel<<<M, 256, 0, stream>>>(x, ln1_g + (long)l * DIMD, ln1_b + (long)l * DIMD, h_bf, nullptr, DIMD);
    // qkv (+gate) = h @ [Wq|Wk|Wv|Wg]   (128-tile, mode 2)
    mfma_gemm128<<<dim3(QKVNP / 128, MB128), 256, 0, stream>>>(h_bf, wqkv_t, nullptr, nullptr, nullptr, qkv_bf, gb, M, QKVNP, DIMD, 2);
    // kw/vw build + fused ck/cv GEMM (one dispatch)
    kwbuild_kernel<<<MCK, 256, 0, stream>>>(qkv_bf, kpe_l, vpe_l, kwm, vwm);
    ckcv_gemm<<<dim3(1, (MCK + 63) / 64, 2), 256, 0, stream>>>(kwm, vwm, wkc_t, wvc_t, ckb, cvb);
    // Vext^T
    vtrans_kernel<<<dim3(13, BATCH * NH), 256, 0, stream>>>(qkv_bf, cvb, Vt);
    // merged dense + compressed score GEMMs
    score_kernel<<<dim3(13, 10, BATCH * NH), 256, 0, stream>>>(qkv_bf, ckb, Sf, Scb, scale);
    // gated probability rows
    prob_kernel<<<BATCH * NH * NC, 256, 0, stream>>>(Sf, Scb, gb, P);
    // comb = P @ Vext
    pv_gemm<<<dim3(10, BATCH * NH), 256, 0, stream>>>(P, Vt, comb_bf);
    // x = comb @ Wo + x   (128-tile, mode 0)
    mfma_gemm128<<<dim3(DIMD / 128, MB128), 256, 0, stream>>>(comb_bf, wo_t, nullptr, x, x, nullptr, nullptr, M, DIMD, DIMD, 0);
    // h = LN2(x) -> bf16
    ln_kernel<<<M, 256, 0, stream>>>(x, ln2_g + (long)l * DIMD, ln2_b + (long)l * DIMD, h_bf, nullptr, DIMD);
    // ff1 = gelu(h @ W1 + b1) -> bf16  (128-tile, mode 1)
    mfma_gemm128<<<dim3(MLPD / 128, MB128), 256, 0, stream>>>(h_bf, w1_t, b1_l, nullptr, nullptr, ff1_bf, nullptr, M, MLPD, DIMD, 1);
    // x = ff1 @ W2 + b2 + x  (128-tile, mode 0)
    mfma_gemm128<<<dim3(DIMD / 128, MB128), 256, 0, stream>>>(ff1_bf, w2_t, b2_l, x, x, nullptr, nullptr, M, DIMD, MLPD, 0);
  }

  // final: LN(x[:,0]) -> head
  ln_kernel<<<BATCH, 256, 0, stream>>>(x, hln_g, hln_b, nullptr, hfin, (long)NTOK * DIMD);
  head_kernel<<<dim3((NCLSD + 255) / 256, BATCH), 256, 0, stream>>>(hfin, head_w, head_b, out);
}

// Round 7
// 388.440 us; speedup vs baseline: 1.7463x; 1.7463x over previous
//
#include <hip/hip_runtime.h>
#include <math.h>

// SparseViT forward. Round 7: revert to 64x64-tile MFMA GEMMs (round-5 engine),
// keep qkv+gate fusion and merged ck/cv from round 6, add split-K (atomicAdd)
// for wo and ff2. B=2, N=577, DIM=512, H=8, DH=64, DEPTH=2, MLP=2048, NCLS=1000

#define NTOK 577
#define DIMD 512
#define NH 8
#define DHD 64
#define NC 145
#define NSB 10
#define KSELD 4
#define SBD 64
#define CBD 16
#define CSD 4
#define SWD 32
#define MLPD 2048
#define NCLSD 1000
#define BATCH 2
#define QKVN 1536    // q|k|v columns (output stride)
#define QKVNG 1600   // + 64 gate cols
#define SFSTRIDE 592
#define SCSTRIDE 160
#define PSTRIDE 832  // 640 token cols + 192 compressed cols

typedef unsigned short ushort;
typedef __attribute__((ext_vector_type(8))) short short8;
typedef __attribute__((ext_vector_type(4))) short short4v;
typedef __attribute__((ext_vector_type(4))) float f32x4;

__device__ __forceinline__ ushort bf16_rne(float f) {
  union { float f; unsigned u; } v; v.f = f;
  unsigned u = v.u;
  unsigned r = (u + 0x7fffu + ((u >> 16) & 1u)) >> 16;
  return (ushort)r;
}
__device__ __forceinline__ float bf16_to_f(ushort s) {
  union { unsigned u; float f; } v; v.u = ((unsigned)s) << 16;
  return v.f;
}
__device__ __forceinline__ int imin(int a, int b) { return a < b ? a : b; }
__device__ __forceinline__ int imax(int a, int b) { return a > b ? a : b; }

// ---------------- patch embed + cls + pos ----------------
__global__ void patch_kernel(const float* __restrict__ img, const float* __restrict__ pw,
                             const float* __restrict__ pb, const float* __restrict__ pos,
                             const float* __restrict__ cls, float* __restrict__ x) {
  int idx = blockIdx.x * 256 + threadIdx.x;
  const int total = BATCH * NTOK * DIMD;
  if (idx >= total) return;
  int d = idx & (DIMD - 1);
  int i = (idx / DIMD) % NTOK;
  int b = idx / (DIMD * NTOK);
  float val;
  if (i == 0) {
    val = cls[d];
  } else {
    int p = i - 1;
    val = pb[d];
#pragma unroll
    for (int c = 0; c < 3; ++c)
      val += img[b * 3 * 576 + c * 576 + p] * pw[c * DIMD + d];
  }
  x[idx] = val + pos[i * DIMD + d];
}

// ---------------- layernorm ----------------
__global__ void ln_kernel(const float* __restrict__ x, const float* __restrict__ g,
                          const float* __restrict__ bb, ushort* __restrict__ out_bf,
                          float* __restrict__ out_f, long rstride) {
  int row = blockIdx.x;
  const float* xr = x + (long)row * rstride;
  int t = threadIdx.x;
  float a = xr[t], c = xr[t + 256];
  __shared__ float s1[256], s2[256];
  s1[t] = a + c;
  s2[t] = a * a + c * c;
  __syncthreads();
  for (int off = 128; off > 0; off >>= 1) {
    if (t < off) { s1[t] += s1[t + off]; s2[t] += s2[t + off]; }
    __syncthreads();
  }
  float m = s1[0] * (1.0f / 512.0f);
  float var = s2[0] * (1.0f / 512.0f) - m * m;
  float r = rsqrtf(var + 1e-5f);
  float o0 = (a - m) * r * g[t] + bb[t];
  float o1 = (c - m) * r * g[t + 256] + bb[t + 256];
  if (out_bf) {
    out_bf[(long)row * DIMD + t] = bf16_rne(o0);
    out_bf[(long)row * DIMD + t + 256] = bf16_rne(o1);
  }
  if (out_f) {
    out_f[(long)row * DIMD + t] = o0;
    out_f[(long)row * DIMD + t + 256] = o1;
  }
}

// ---------------- ALL weight transposes for one layer in ONE dispatch ----------------
__global__ void wtrans_all_kernel(const float* __restrict__ Wq, const float* __restrict__ Wk,
                                  const float* __restrict__ Wv, const float* __restrict__ Wg,
                                  const float* __restrict__ Wo, const float* __restrict__ Wkc,
                                  const float* __restrict__ Wvc, const float* __restrict__ w1,
                                  const float* __restrict__ w2,
                                  ushort* __restrict__ wqkv_t, ushort* __restrict__ wo_t,
                                  ushort* __restrict__ w1_t, ushort* __restrict__ w2_t,
                                  ushort* __restrict__ wkc_t, ushort* __restrict__ wvc_t) {
  __shared__ float tile[32][33];
  int t = blockIdx.x;
  const float* W; ushort* Wt; int K, N, bx, by;
  if (t < 768) {
    int which = t >> 8, rr = t & 255;
    W = which == 0 ? Wq : (which == 1 ? Wk : Wv);
    Wt = wqkv_t + which * 512 * 512;
    K = 512; N = 512; bx = rr & 15; by = rr >> 4;
  } else if (t < 1024) {
    int rr = t - 768; W = Wo; Wt = wo_t; K = 512; N = 512; bx = rr & 15; by = rr >> 4;
  } else if (t < 2048) {
    int rr = t - 1024; W = w1; Wt = w1_t; K = 512; N = 2048; bx = rr & 63; by = rr >> 6;
  } else if (t < 3072) {
    int rr = t - 2048; W = w2; Wt = w2_t; K = 2048; N = 512; bx = rr & 15; by = rr >> 4;
  } else if (t < 3104) {
    // gate: into wqkv_t rows 1536..1599 (N=24 real, zero-padded to 64)
    int rr = t - 3072; W = Wg; Wt = wqkv_t + (long)1536 * 512; K = 512; N = 24; bx = rr & 1; by = rr >> 1;
  } else if (t < 3168) {
    int rr = t - 3104; W = Wkc; Wt = wkc_t; K = 1024; N = 64; bx = rr & 1; by = rr >> 1;
  } else {
    int rr = t - 3168; W = Wvc; Wt = wvc_t; K = 1024; N = 64; bx = rr & 1; by = rr >> 1;
  }
  int k0 = by * 32, n0 = bx * 32;
  int tx = threadIdx.x, ty = threadIdx.y;
#pragma unroll
  for (int r = 0; r < 32; r += 8)
    tile[ty + r][tx] = (n0 + tx < N) ? W[(long)(k0 + ty + r) * N + n0 + tx] : 0.f;
  __syncthreads();
#pragma unroll
  for (int r = 0; r < 32; r += 8)
    Wt[(long)(n0 + ty + r) * K + k0 + tx] = bf16_rne(tile[tx][ty + r]);
}

// ---------------- 64x64-tile bf16 MFMA GEMM ----------------
// mode 1: Cbf = gelu(acc + bias)                 (bf16, stride N)
// mode 2: qkv+gate: col<1536 -> Cbf (stride 1536); col in [1536,1600) -> sigmoid -> gb
// mode 4: atomicAdd(Cf, acc + (z==0 ? bias : 0)) (split-K; resid pre-resident in Cf)
// K range: [blockIdx.z*kSlice, min(K, +kSlice))
__global__ __launch_bounds__(256) void mfma_gemm(
    const ushort* __restrict__ A, const ushort* __restrict__ Bt,
    const float* __restrict__ bias,
    float* __restrict__ Cf, ushort* __restrict__ Cbf, float* __restrict__ gb,
    int M, int N, int K, int kSlice, int mode) {
  __shared__ short As[64][72];
  __shared__ short Bs[64][72];
  int tid = threadIdx.x;
  int lane = tid & 63, wave = tid >> 6;
  int wm = wave >> 1, wn = wave & 1;
  int rowBase = blockIdx.y * 64, colBase = blockIdx.x * 64;
  int m = lane & 15, kg = lane >> 4;
  int kBeg = blockIdx.z * kSlice;
  int kEnd = imin(K, kBeg + kSlice);
  f32x4 acc[2][2] = {};
  for (int k0 = kBeg; k0 < kEnd; k0 += 64) {
#pragma unroll
    for (int cc = 0; cc < 2; ++cc) {
      int c = tid * 2 + cc;
      int r = c >> 3, kc = c & 7;
      short8 av = {};
      int gr = rowBase + r;
      if (gr < M) av = *(const short8*)(A + (long)gr * K + k0 + kc * 8);
      *(short8*)&As[r][kc * 8] = av;
      short8 bv = *(const short8*)(Bt + (long)(colBase + r) * K + k0 + kc * 8);
      *(short8*)&Bs[r][kc * 8] = bv;
    }
    __syncthreads();
#pragma unroll
    for (int ks = 0; ks < 2; ++ks) {
      short8 a0 = *(const short8*)&As[wm * 32 + m][ks * 32 + kg * 8];
      short8 a1 = *(const short8*)&As[wm * 32 + 16 + m][ks * 32 + kg * 8];
      short8 b0 = *(const short8*)&Bs[wn * 32 + m][ks * 32 + kg * 8];
      short8 b1 = *(const short8*)&Bs[wn * 32 + 16 + m][ks * 32 + kg * 8];
      acc[0][0] = __builtin_amdgcn_mfma_f32_16x16x32_bf16(a0, b0, acc[0][0], 0, 0, 0);
      acc[0][1] = __builtin_amdgcn_mfma_f32_16x16x32_bf16(a0, b1, acc[0][1], 0, 0, 0);
      acc[1][0] = __builtin_amdgcn_mfma_f32_16x16x32_bf16(a1, b0, acc[1][0], 0, 0, 0);
      acc[1][1] = __builtin_amdgcn_mfma_f32_16x16x32_bf16(a1, b1, acc[1][1], 0, 0, 0);
    }
    __syncthreads();
  }
#pragma unroll
  for (int mt = 0; mt < 2; ++mt)
#pragma unroll
    for (int nt = 0; nt < 2; ++nt) {
      int col = colBase + wn * 32 + nt * 16 + m;
#pragma unroll
      for (int r = 0; r < 4; ++r) {
        int row = rowBase + wm * 32 + mt * 16 + kg * 4 + r;
        if (row >= M) continue;
        float v = acc[mt][nt][r];
        if (mode == 2) {
          if (col < QKVN) Cbf[(long)row * QKVN + col] = bf16_rne(v);
          else if (col < QKVNG) gb[(long)row * 64 + (col - QKVN)] = 1.f / (1.f + __expf(-v));
        } else if (mode == 1) {
          v += bias[col];
          float u = 0.7978845608028654f * (v + 0.044715f * v * v * v);
          v = 0.5f * v * (1.f + tanhf(u));
          Cbf[(long)row * N + col] = bf16_rne(v);
        } else {  // mode 4
          if (bias && blockIdx.z == 0) v += bias[col];
          atomicAdd(&Cf[(long)row * N + col], v);
        }
      }
    }
}

// ---------------- ck/cv: both halves in one dispatch (z selects) ----------------
__global__ __launch_bounds__(256) void ckcv_gemm(
    const ushort* __restrict__ kwm, const ushort* __restrict__ vwm,
    const ushort* __restrict__ wkc_t, const ushort* __restrict__ wvc_t,
    ushort* __restrict__ ckb, ushort* __restrict__ cvb) {
  const ushort* A = blockIdx.z ? vwm : kwm;
  const ushort* Bt = blockIdx.z ? wvc_t : wkc_t;
  ushort* C = blockIdx.z ? cvb : ckb;
  const int M = BATCH * NH * NC, N = 64, K = 1024;
  __shared__ short As[64][72];
  __shared__ short Bs[64][72];
  int tid = threadIdx.x;
  int lane = tid & 63, wave = tid >> 6;
  int wm = wave >> 1, wn = wave & 1;
  int rowBase = blockIdx.y * 64;
  int m = lane & 15, kg = lane >> 4;
  f32x4 acc[2][2] = {};
  for (int k0 = 0; k0 < K; k0 += 64) {
#pragma unroll
    for (int cc = 0; cc < 2; ++cc) {
      int c = tid * 2 + cc;
      int r = c >> 3, kc = c & 7;
      short8 av = {};
      int gr = rowBase + r;
      if (gr < M) av = *(const short8*)(A + (long)gr * K + k0 + kc * 8);
      *(short8*)&As[r][kc * 8] = av;
      short8 bv = *(const short8*)(Bt + (long)r * K + k0 + kc * 8);
      *(short8*)&Bs[r][kc * 8] = bv;
    }
    __syncthreads();
#pragma unroll
    for (int ks = 0; ks < 2; ++ks) {
      short8 a0 = *(const short8*)&As[wm * 32 + m][ks * 32 + kg * 8];
      short8 a1 = *(const short8*)&As[wm * 32 + 16 + m][ks * 32 + kg * 8];
      short8 b0 = *(const short8*)&Bs[wn * 32 + m][ks * 32 + kg * 8];
      short8 b1 = *(const short8*)&Bs[wn * 32 + 16 + m][ks * 32 + kg * 8];
      acc[0][0] = __builtin_amdgcn_mfma_f32_16x16x32_bf16(a0, b0, acc[0][0], 0, 0, 0);
      acc[0][1] = __builtin_amdgcn_mfma_f32_16x16x32_bf16(a0, b1, acc[0][1], 0, 0, 0);
      acc[1][0] = __builtin_amdgcn_mfma_f32_16x16x32_bf16(a1, b0, acc[1][0], 0, 0, 0);
      acc[1][1] = __builtin_amdgcn_mfma_f32_16x16x32_bf16(a1, b1, acc[1][1], 0, 0, 0);
    }
    __syncthreads();
  }
#pragma unroll
  for (int mt = 0; mt < 2; ++mt)
#pragma unroll
    for (int nt = 0; nt < 2; ++nt) {
      int col = wn * 32 + nt * 16 + m;
#pragma unroll
      for (int r = 0; r < 4; ++r) {
        int row = rowBase + wm * 32 + mt * 16 + kg * 4 + r;
        if (row < M) C[(long)row * N + col] = bf16_rne(acc[mt][nt][r]);
      }
    }
}

// ---------------- batched score GEMM: merged dense (x<10) + compressed (x>=10) ----------------
__global__ __launch_bounds__(256) void score_kernel(
    const ushort* __restrict__ qkv_bf, const ushort* __restrict__ ckb,
    ushort* __restrict__ Sf, ushort* __restrict__ Scb, float scale) {
  __shared__ short As[64][72];
  __shared__ short Bs[64][72];
  int z = blockIdx.z;
  int b = z >> 3, h = z & 7;
  int i0 = blockIdx.y * 64;
  int xb = blockIdx.x;
  bool isC = xb >= 10;
  int j0 = (isC ? (xb - 10) : xb) * 64;
  int tid = threadIdx.x;
  int lane = tid & 63, wave = tid >> 6;
  int wm = wave >> 1, wn = wave & 1;
  const ushort* aBase = qkv_bf + (long)b * NTOK * QKVN + h * 64;
  const ushort* bBase = aBase + 512;
  const ushort* cBase = ckb + (long)z * NC * DHD;
#pragma unroll
  for (int rep = 0; rep < 4; ++rep) {
    int row = rep * 16 + (tid >> 4);
    int c4 = tid & 15;
    int gi = i0 + row;
    short4v a16 = {};
    if (gi < NTOK) a16 = *(const short4v*)(aBase + (long)gi * QKVN + c4 * 4);
    *(short4v*)&As[row][c4 * 4] = a16;
    int gj = j0 + row;
    short4v b16 = {};
    if (isC) {
      if (gj < NC) b16 = *(const short4v*)(cBase + (long)gj * DHD + c4 * 4);
    } else {
      if (gj < NTOK) b16 = *(const short4v*)(bBase + (long)gj * QKVN + c4 * 4);
    }
    *(short4v*)&Bs[row][c4 * 4] = b16;
  }
  __syncthreads();
  int m = lane & 15, kg = lane >> 4;
  f32x4 acc[2][2] = {};
#pragma unroll
  for (int ks = 0; ks < 2; ++ks) {
    short8 a0 = *(const short8*)&As[wm * 32 + m][ks * 32 + kg * 8];
    short8 a1 = *(const short8*)&As[wm * 32 + 16 + m][ks * 32 + kg * 8];
    short8 b0 = *(const short8*)&Bs[wn * 32 + m][ks * 32 + kg * 8];
    short8 b1 = *(const short8*)&Bs[wn * 32 + 16 + m][ks * 32 + kg * 8];
    acc[0][0] = __builtin_amdgcn_mfma_f32_16x16x32_bf16(a0, b0, acc[0][0], 0, 0, 0);
    acc[0][1] = __builtin_amdgcn_mfma_f32_16x16x32_bf16(a0, b1, acc[0][1], 0, 0, 0);
    acc[1][0] = __builtin_amdgcn_mfma_f32_16x16x32_bf16(a1, b0, acc[1][0], 0, 0, 0);
    acc[1][1] = __builtin_amdgcn_mfma_f32_16x16x32_bf16(a1, b1, acc[1][1], 0, 0, 0);
  }
  int nvalid = isC ? NC : NTOK;
  int sstride = isC ? SCSTRIDE : SFSTRIDE;
  ushort* Sz = (isC ? Scb : Sf) + (long)z * NTOK * sstride;
#pragma unroll
  for (int mt = 0; mt < 2; ++mt)
#pragma unroll
    for (int nt = 0; nt < 2; ++nt) {
      int col = j0 + wn * 32 + nt * 16 + m;
#pragma unroll
      for (int r = 0; r < 4; ++r) {
        int row = i0 + wm * 32 + mt * 16 + kg * 4 + r;
        if (row < NTOK && col < nvalid)
          Sz[(long)row * sstride + col] = bf16_rne(acc[mt][nt][r] * scale);
      }
    }
}

// ---------------- kw/vw build from bf16 qkv ----------------
__global__ void kwbuild_kernel(const ushort* __restrict__ qkv_bf,
                               const float* __restrict__ kpe, const float* __restrict__ vpe,
                               ushort* __restrict__ kwm, ushort* __restrict__ vwm) {
  int r = blockIdx.x;               // 0..2319
  int j = r % NC;
  int bh = r / NC;
  int h = bh & 7, b = bh >> 3;
  int t = threadIdx.x >> 4;
  int d4 = threadIdx.x & 15;
  int tok = j * CSD + t;
  float k0 = 0.f, k1 = 0.f, k2 = 0.f, k3 = 0.f, v0 = 0.f, v1 = 0.f, v2 = 0.f, v3 = 0.f;
  if (tok < NTOK) {
    const ushort* base = qkv_bf + (long)(b * NTOK + tok) * QKVN + h * DHD + d4 * 4;
    short4v kv = *(const short4v*)(base + 512);
    short4v vv = *(const short4v*)(base + 1024);
    k0 = bf16_to_f((ushort)kv.x); k1 = bf16_to_f((ushort)kv.y);
    k2 = bf16_to_f((ushort)kv.z); k3 = bf16_to_f((ushort)kv.w);
    v0 = bf16_to_f((ushort)vv.x); v1 = bf16_to_f((ushort)vv.y);
    v2 = bf16_to_f((ushort)vv.z); v3 = bf16_to_f((ushort)vv.w);
  }
  float4 kp = *(const float4*)(kpe + t * DHD + d4 * 4);
  float4 vp = *(const float4*)(vpe + t * DHD + d4 * 4);
  short4v ko, vo;
  ko.x = (short)bf16_rne(k0 + kp.x); ko.y = (short)bf16_rne(k1 + kp.y);
  ko.z = (short)bf16_rne(k2 + kp.z); ko.w = (short)bf16_rne(k3 + kp.w);
  vo.x = (short)bf16_rne(v0 + vp.x); vo.y = (short)bf16_rne(v1 + vp.y);
  vo.z = (short)bf16_rne(v2 + vp.z); vo.w = (short)bf16_rne(v3 + vp.w);
  long ob = (long)r * 1024 + t * DHD + d4 * 4;
  *(short4v*)(kwm + ob) = ko;
  *(short4v*)(vwm + ob) = vo;
}

// ---------------- Vext^T build ----------------
__global__ void vtrans_kernel(const ushort* __restrict__ qkv_bf, const ushort* __restrict__ cvb,
                              ushort* __restrict__ Vt) {
  int kt = blockIdx.x;   // 0..12
  int z = blockIdx.y;    // 0..15
  int b = z >> 3, h = z & 7;
  __shared__ short tile[64][72];
  int tid = threadIdx.x;
  int r = tid >> 2, seg = tid & 3;
  short8 a0 = {}, a1 = {};
  if (kt < 10) {
    int tok = kt * 64 + r;
    if (tok < NTOK) {
      const ushort* src = qkv_bf + (long)(b * NTOK + tok) * QKVN + 1024 + h * 64 + seg * 16;
      a0 = *(const short8*)src;
      a1 = *(const short8*)(src + 8);
    }
  } else {
    int cr = (kt - 10) * 64 + r;
    if (cr < NC) {
      const ushort* src = cvb + ((long)z * NC + cr) * DHD + seg * 16;
      a0 = *(const short8*)src;
      a1 = *(const short8*)(src + 8);
    }
  }
  *(short8*)&tile[r][seg * 16] = a0;
  *(short8*)&tile[r][seg * 16 + 8] = a1;
  __syncthreads();
  int d = tid >> 2;
  short8 o0, o1;
#pragma unroll
  for (int q = 0; q < 8; ++q) o0[q] = tile[seg * 16 + q][d];
#pragma unroll
  for (int q = 0; q < 8; ++q) o1[q] = tile[seg * 16 + 8 + q][d];
  ushort* dst = Vt + ((long)z * 64 + d) * PSTRIDE + kt * 64 + seg * 16;
  *(short8*)dst = o0;
  *(short8*)(dst + 8) = o1;
}

// ---------------- prob: softmax + top-k + gates -> dense gated P row ----------------
__global__ __launch_bounds__(256, 4) void prob_kernel(
    const ushort* __restrict__ Sf, const ushort* __restrict__ Scb,
    const float* __restrict__ gb, ushort* __restrict__ P) {
  int qt = blockIdx.x % NC;
  int z = blockIdx.x / NC;
  int h = z & 7, b = z >> 3;
  int tid = threadIdx.x, lane = tid & 63, w = tid >> 6;
  int i0 = qt * 4 + w;
  bool valid = i0 < NTOK;
  int i = imin(i0, NTOK - 1);

  __shared__ float scL[4][192];
  __shared__ float ssL[4][256];
  __shared__ float swL[4][32];
  __shared__ float impL[4][16];
  __shared__ int selL[4][KSELD];
  float* sc = scL[w]; float* ss = ssL[w];
  float* swv = swL[w]; float* imp = impL[w]; int* sel = selL[w];

  const ushort* scRow = Scb + ((long)z * NTOK + i) * SCSTRIDE;
  const ushort* sfRow = Sf + ((long)z * NTOK + i) * SFSTRIDE;

  float e[3], mC = -1e30f;
#pragma unroll
  for (int c = 0; c < 3; ++c) {
    int j = c * 64 + lane;
    float s = bf16_to_f(scRow[imin(j, NC - 1)]);
    s = (j < NC) ? s : -1e30f;
    e[c] = s;
    mC = fmaxf(mC, s);
  }
#pragma unroll
  for (int msk = 1; msk < 64; msk <<= 1) mC = fmaxf(mC, __shfl_xor(mC, msk, 64));
  float sumC = 0.f;
#pragma unroll
  for (int c = 0; c < 3; ++c) {
    float ev = (e[c] > -1e29f) ? __expf(e[c] - mC) : 0.f;
    sc[c * 64 + lane] = ev;
    sumC += ev;
  }
#pragma unroll
  for (int msk = 1; msk < 64; msk <<= 1) sumC += __shfl_xor(sumC, msk, 64);
  __syncthreads();

  if (lane < NSB) {
    int lo = imax(0, 16 * lane - 2), hi = imin(NC - 1, 16 * lane + 13);
    float s = 0.f;
    for (int j = lo; j <= hi; ++j) s += sc[j];
    imp[lane] = s;
  }
  __syncthreads();
  if (lane == 0) {
    unsigned used = 0;
    for (int r = 0; r < KSELD; ++r) {
      int bi = 0; float bv = -1e30f;
      for (int s = 0; s < NSB; ++s)
        if (!((used >> s) & 1u) && imp[s] > bv) { bv = imp[s]; bi = s; }
      used |= 1u << bi;
      sel[r] = bi;
    }
  }
  __syncthreads();

  float es[4], mS = -1e30f;
#pragma unroll
  for (int c = 0; c < 4; ++c) {
    int tok = sel[c] * SBD + lane;
    float s = bf16_to_f(sfRow[imin(tok, NTOK - 1)]);
    s = (tok < NTOK) ? s : -1e30f;
    es[c] = s;
    mS = fmaxf(mS, s);
  }
#pragma unroll
  for (int msk = 1; msk < 64; msk <<= 1) mS = fmaxf(mS, __shfl_xor(mS, msk, 64));
  float sumS = 0.f;
#pragma unroll
  for (int c = 0; c < 4; ++c) {
    float ev = (es[c] > -1e29f) ? __expf(es[c] - mS) : 0.f;
    ss[c * 64 + lane] = ev;
    sumS += ev;
  }
#pragma unroll
  for (int msk = 1; msk < 64; msk <<= 1) sumS += __shfl_xor(sumS, msk, 64);

  float sw_s;
  {
    int pos = i + (lane & 31) - SWD / 2;
    float s = bf16_to_f(sfRow[imin(imax(pos, 0), NTOK - 1)]);
    sw_s = (pos >= 0 && pos < NTOK) ? s : -1e30f;
  }
  float mW = sw_s;
#pragma unroll
  for (int msk = 1; msk < 32; msk <<= 1) mW = fmaxf(mW, __shfl_xor(mW, msk, 64));
  float ew = (sw_s > -1e29f) ? __expf(sw_s - mW) : 0.f;
  float sumW = ew;
#pragma unroll
  for (int msk = 1; msk < 32; msk <<= 1) sumW += __shfl_xor(sumW, msk, 64);
  if (lane < SWD) swv[lane] = ew;
  __syncthreads();

  if (!valid) return;
  const float* gp = gb + (long)(b * NTOK + i) * 64 + h * 3;
  float rC = gp[0] / sumC, rS = gp[1] / sumS, rW = gp[2] / sumW;
  ushort* prow = P + ((long)z * NTOK + i0) * PSTRIDE;
#pragma unroll
  for (int c = 0; c < 10; ++c) {
    int col = c * 64 + lane;
    float val = 0.f;
#pragma unroll
    for (int r = 0; r < 4; ++r)
      if (sel[r] == c) val += rS * ss[r * 64 + lane];
    int t = col - i + 16;
    if (t >= 0 && t < SWD && col < NTOK) val += rW * swv[t];
    prow[col] = bf16_rne(val);
  }
#pragma unroll
  for (int c = 0; c < 3; ++c) {
    int j = c * 64 + lane;
    float val = (j < NC) ? rC * sc[j] : 0.f;
    prow[640 + j] = bf16_rne(val);
  }
}

// ---------------- PV GEMM: comb[b,i,h*64+d] = P[z] @ Vext[z] ----------------
__global__ __launch_bounds__(256) void pv_gemm(const ushort* __restrict__ P,
                                               const ushort* __restrict__ Vt,
                                               ushort* __restrict__ comb) {
  __shared__ short As[64][72];
  __shared__ short Bs[64][72];
  int z = blockIdx.y;
  int b = z >> 3, h = z & 7;
  int rowBase = blockIdx.x * 64;
  int tid = threadIdx.x;
  int lane = tid & 63, wave = tid >> 6;
  int wm = wave >> 1, wn = wave & 1;
  const ushort* Pz = P + (long)z * NTOK * PSTRIDE;
  const ushort* Vz = Vt + (long)z * 64 * PSTRIDE;
  int m = lane & 15, kg = lane >> 4;
  f32x4 acc[2][2] = {};
  for (int k0 = 0; k0 < PSTRIDE; k0 += 64) {
#pragma unroll
    for (int cc = 0; cc < 2; ++cc) {
      int c = tid * 2 + cc;
      int r = c >> 3, kc = c & 7;
      short8 av = {};
      int gr = rowBase + r;
      if (gr < NTOK) av = *(const short8*)(Pz + (long)gr * PSTRIDE + k0 + kc * 8);
      *(short8*)&As[r][kc * 8] = av;
      short8 bv = *(const short8*)(Vz + (long)r * PSTRIDE + k0 + kc * 8);
      *(short8*)&Bs[r][kc * 8] = bv;
    }
    __syncthreads();
#pragma unroll
    for (int ks = 0; ks < 2; ++ks) {
      short8 a0 = *(const short8*)&As[wm * 32 + m][ks * 32 + kg * 8];
      short8 a1 = *(const short8*)&As[wm * 32 + 16 + m][ks * 32 + kg * 8];
      short8 b0 = *(const short8*)&Bs[wn * 32 + m][ks * 32 + kg * 8];
      short8 b1 = *(const short8*)&Bs[wn * 32 + 16 + m][ks * 32 + kg * 8];
      acc[0][0] = __builtin_amdgcn_mfma_f32_16x16x32_bf16(a0, b0, acc[0][0], 0, 0, 0);
      acc[0][1] = __builtin_amdgcn_mfma_f32_16x16x32_bf16(a0, b1, acc[0][1], 0, 0, 0);
      acc[1][0] = __builtin_amdgcn_mfma_f32_16x16x32_bf16(a1, b0, acc[1][0], 0, 0, 0);
      acc[1][1] = __builtin_amdgcn_mfma_f32_16x16x32_bf16(a1, b1, acc[1][1], 0, 0, 0);
    }
    __syncthreads();
  }
#pragma unroll
  for (int mt = 0; mt < 2; ++mt)
#pragma unroll
    for (int nt = 0; nt < 2; ++nt) {
      int col = wn * 32 + nt * 16 + m;
#pragma unroll
      for (int r = 0; r < 4; ++r) {
        int row = rowBase + wm * 32 + mt * 16 + kg * 4 + r;
        if (row < NTOK)
          comb[(long)(b * NTOK + row) * DIMD + h * 64 + col] = bf16_rne(acc[mt][nt][r]);
      }
    }
}

// ---------------- head ----------------
__global__ void head_kernel(const float* __restrict__ hfin, const float* __restrict__ W,
                            const float* __restrict__ bias, float* __restrict__ out) {
  __shared__ float hs[512];
  int bidx = blockIdx.y;
  int t = threadIdx.x;
  hs[t] = hfin[bidx * 512 + t];
  hs[t + 256] = hfin[bidx * 512 + t + 256];
  __syncthreads();
  int col = blockIdx.x * 256 + t;
  if (col < NCLSD) {
    float acc = bias[col];
#pragma unroll 8
    for (int k = 0; k < 512; ++k) acc += hs[k] * W[(long)k * NCLSD + col];
    out[bidx * NCLSD + col] = acc;
  }
}

extern "C" void kernel_launch(void* const* d_in, const int* in_sizes, int n_in,
                              void* d_out, int out_size, void* d_ws, size_t ws_size,
                              hipStream_t stream) {
  const float* img     = (const float*)d_in[0];
  const float* patch_w = (const float*)d_in[1];
  const float* patch_b = (const float*)d_in[2];
  const float* pos_emb = (const float*)d_in[3];
  const float* cls_tok = (const float*)d_in[4];
  const float* ln1_g   = (const float*)d_in[5];
  const float* ln1_b   = (const float*)d_in[6];
  const float* Wq      = (const float*)d_in[7];
  const float* Wk      = (const float*)d_in[8];
  const float* Wv      = (const float*)d_in[9];
  const float* Wg      = (const float*)d_in[10];
  const float* Wo      = (const float*)d_in[11];
  const float* kpe     = (const float*)d_in[12];
  const float* vpe     = (const float*)d_in[13];
  const float* Wkc     = (const float*)d_in[14];
  const float* Wvc     = (const float*)d_in[15];
  const float* ln2_g   = (const float*)d_in[16];
  const float* ln2_b   = (const float*)d_in[17];
  const float* ff_w1   = (const float*)d_in[18];
  const float* ff_b1   = (const float*)d_in[19];
  const float* ff_w2   = (const float*)d_in[20];
  const float* ff_b2   = (const float*)d_in[21];
  const float* hln_g   = (const float*)d_in[22];
  const float* hln_b   = (const float*)d_in[23];
  const float* head_w  = (const float*)d_in[24];
  const float* head_b  = (const float*)d_in[25];
  float* out = (float*)d_out;

  // ---- workspace carve ----
  char* p = (char*)d_ws;
  const long MROW = (long)BATCH * NTOK;            // 1154
  float* x       = (float*)p;  p += MROW * DIMD * 4;
  ushort* qkv_bf = (ushort*)p; p += MROW * QKVN * 2;
  ushort* h_bf   = (ushort*)p; p += MROW * DIMD * 2;
  ushort* comb_bf= (ushort*)p; p += MROW * DIMD * 2;
  float* gb      = (float*)p;  p += MROW * 64 * 4;
  ushort* ckb    = (ushort*)p; p += (long)BATCH * NH * NC * DHD * 2;
  ushort* cvb    = (ushort*)p; p += (long)BATCH * NH * NC * DHD * 2;
  ushort* Vt     = (ushort*)p; p += (long)BATCH * NH * 64 * PSTRIDE * 2;
  ushort* Scb    = (ushort*)p; p += (long)BATCH * NH * NTOK * SCSTRIDE * 2;
  float* hfin    = (float*)p;  p += BATCH * DIMD * 4;
  ushort* wqkv_t = (ushort*)p; p += (long)1664 * DIMD * 2;   // q|k|v|gate rows (1600 used)
  ushort* wo_t   = (ushort*)p; p += (long)DIMD * DIMD * 2;
  ushort* w1_t   = (ushort*)p; p += (long)MLPD * DIMD * 2;
  ushort* w2_t   = (ushort*)p; p += (long)DIMD * MLPD * 2;
  ushort* wkc_t  = (ushort*)p; p += (long)64 * 1024 * 2;
  ushort* wvc_t  = (ushort*)p; p += (long)64 * 1024 * 2;
  // region A: kwm+vwm aliased with P (disjoint lifetimes)
  ushort* kwm    = (ushort*)p;
  ushort* vwm    = kwm + (long)BATCH * NH * NC * 1024;
  ushort* P      = kwm;
  p += (long)BATCH * NH * NTOK * PSTRIDE * 2;
  // region B: Sf aliased with ff1_bf (disjoint lifetimes)
  ushort* Sf     = (ushort*)p;
  ushort* ff1_bf = Sf;
  p += (long)BATCH * NH * NTOK * SFSTRIDE * 2;

  const int M = (int)MROW;                  // 1154
  const int MB64 = (M + 63) / 64;           // 19
  const int MCK = BATCH * NH * NC;          // 2320
  const float scale = 0.125f;
  dim3 thrT(32, 8);

  patch_kernel<<<(M * DIMD + 255) / 256, 256, 0, stream>>>(img, patch_w, patch_b, pos_emb, cls_tok, x);

  for (int l = 0; l < 2; ++l) {
    const float* Wq_l  = Wq + (long)l * DIMD * DIMD;
    const float* Wk_l  = Wk + (long)l * DIMD * DIMD;
    const float* Wv_l  = Wv + (long)l * DIMD * DIMD;
    const float* Wg_l  = Wg + (long)l * DIMD * 3 * NH;
    const float* Wo_l  = Wo + (long)l * DIMD * DIMD;
    const float* kpe_l = kpe + (long)l * CBD * DHD;
    const float* vpe_l = vpe + (long)l * CBD * DHD;
    const float* Wkc_l = Wkc + (long)l * CBD * DHD * DHD;
    const float* Wvc_l = Wvc + (long)l * CBD * DHD * DHD;
    const float* w1_l  = ff_w1 + (long)l * DIMD * MLPD;
    const float* b1_l  = ff_b1 + (long)l * MLPD;
    const float* w2_l  = ff_w2 + (long)l * MLPD * DIMD;
    const float* b2_l  = ff_b2 + (long)l * DIMD;

    wtrans_all_kernel<<<3232, thrT, 0, stream>>>(Wq_l, Wk_l, Wv_l, Wg_l, Wo_l, Wkc_l, Wvc_l,
                                                 w1_l, w2_l, wqkv_t, wo_t, w1_t, w2_t,
                                                 wkc_t, wvc_t);
    // h = LN1(x) -> bf16
    ln_kernel<<<M, 256, 0, stream>>>(x, ln1_g + (long)l * DIMD, ln1_b + (long)l * DIMD, h_bf, nullptr, DIMD);
    // qkv (+gate) = h @ [Wq|Wk|Wv|Wg]   (mode 2)
    mfma_gemm<<<dim3(QKVNG / 64, MB64), 256, 0, stream>>>(h_bf, wqkv_t, nullptr, nullptr, qkv_bf, gb, M, QKVNG, DIMD, DIMD, 2);
    // kw/vw build + merged ck/cv GEMM
    kwbuild_kernel<<<MCK, 256, 0, stream>>>(qkv_bf, kpe_l, vpe_l, kwm, vwm);
    ckcv_gemm<<<dim3(1, (MCK + 63) / 64, 2), 256, 0, stream>>>(kwm, vwm, wkc_t, wvc_t, ckb, cvb);
    // Vext^T
    vtrans_kernel<<<dim3(13, BATCH * NH), 256, 0, stream>>>(qkv_bf, cvb, Vt);
    // merged dense + compressed score GEMMs
    score_kernel<<<dim3(13, 10, BATCH * NH), 256, 0, stream>>>(qkv_bf, ckb, Sf, Scb, scale);
    // gated probability rows
    prob_kernel<<<BATCH * NH * NC, 256, 0, stream>>>(Sf, Scb, gb, P);
    // comb = P @ Vext
    pv_gemm<<<dim3(10, BATCH * NH), 256, 0, stream>>>(P, Vt, comb_bf);
    // x += comb @ Wo   (mode 4, split-K=2)
    mfma_gemm<<<dim3(DIMD / 64, MB64, 2), 256, 0, stream>>>(comb_bf, wo_t, nullptr, x, nullptr, nullptr, M, DIMD, DIMD, 256, 4);
    // h = LN2(x) -> bf16
    ln_kernel<<<M, 256, 0, stream>>>(x, ln2_g + (long)l * DIMD, ln2_b + (long)l * DIMD, h_bf, nullptr, DIMD);
    // ff1 = gelu(h @ W1 + b1) -> bf16  (mode 1)
    mfma_gemm<<<dim3(MLPD / 64, MB64), 256, 0, stream>>>(h_bf, w1_t, b1_l, nullptr, ff1_bf, nullptr, M, MLPD, DIMD, DIMD, 1);
    // x += ff1 @ W2 + b2   (mode 4, split-K=4)
    mfma_gemm<<<dim3(DIMD / 64, MB64, 4), 256, 0, stream>>>(ff1_bf, w2_t, b2_l, x, nullptr, nullptr, M, DIMD, MLPD, 512, 4);
  }

  // final: LN(x[:,0]) -> head
  ln_kernel<<<BATCH, 256, 0, stream>>>(x, hln_g, hln_b, nullptr, hfin, (long)NTOK * DIMD);
  head_kernel<<<dim3((NCLSD + 255) / 256, BATCH), 256, 0, stream>>>(hfin, head_w, head_b, out);
}

// Round 8
// 379.420 us; speedup vs baseline: 1.7878x; 1.0238x over previous
//
#include <hip/hip_runtime.h>
#include <math.h>

// SparseViT forward. Round 8: dispatch-count reduction. Single wtrans for both
// layers; vtrans eliminated (V-part merged into kwbuild, CV computed transposed
// straight into Vt); final LN fused into head. 25 dispatches total.
// B=2, N=577, DIM=512, H=8, DH=64, DEPTH=2, MLP=2048, NCLS=1000, nc=145, ns=10

#define NTOK 577
#define DIMD 512
#define NH 8
#define DHD 64
#define NC 145
#define NSB 10
#define KSELD 4
#define SBD 64
#define CBD 16
#define CSD 4
#define SWD 32
#define MLPD 2048
#define NCLSD 1000
#define BATCH 2
#define QKVN 1536    // q|k|v columns (output stride)
#define QKVNG 1600   // + 64 gate cols
#define SFSTRIDE 592
#define SCSTRIDE 160
#define PSTRIDE 832  // 640 token cols + 192 compressed cols
#define MCKD 2320    // BATCH*NH*NC

typedef unsigned short ushort;
typedef __attribute__((ext_vector_type(8))) short short8;
typedef __attribute__((ext_vector_type(4))) short short4v;
typedef __attribute__((ext_vector_type(4))) float f32x4;

__device__ __forceinline__ ushort bf16_rne(float f) {
  union { float f; unsigned u; } v; v.f = f;
  unsigned u = v.u;
  unsigned r = (u + 0x7fffu + ((u >> 16) & 1u)) >> 16;
  return (ushort)r;
}
__device__ __forceinline__ float bf16_to_f(ushort s) {
  union { unsigned u; float f; } v; v.u = ((unsigned)s) << 16;
  return v.f;
}
__device__ __forceinline__ int imin(int a, int b) { return a < b ? a : b; }
__device__ __forceinline__ int imax(int a, int b) { return a > b ? a : b; }

// ---------------- patch embed + cls + pos ----------------
__global__ void patch_kernel(const float* __restrict__ img, const float* __restrict__ pw,
                             const float* __restrict__ pb, const float* __restrict__ pos,
                             const float* __restrict__ cls, float* __restrict__ x) {
  int idx = blockIdx.x * 256 + threadIdx.x;
  const int total = BATCH * NTOK * DIMD;
  if (idx >= total) return;
  int d = idx & (DIMD - 1);
  int i = (idx / DIMD) % NTOK;
  int b = idx / (DIMD * NTOK);
  float val;
  if (i == 0) {
    val = cls[d];
  } else {
    int p = i - 1;
    val = pb[d];
#pragma unroll
    for (int c = 0; c < 3; ++c)
      val += img[b * 3 * 576 + c * 576 + p] * pw[c * DIMD + d];
  }
  x[idx] = val + pos[i * DIMD + d];
}

// ---------------- layernorm ----------------
__global__ void ln_kernel(const float* __restrict__ x, const float* __restrict__ g,
                          const float* __restrict__ bb, ushort* __restrict__ out_bf) {
  int row = blockIdx.x;
  const float* xr = x + (long)row * DIMD;
  int t = threadIdx.x;
  float a = xr[t], c = xr[t + 256];
  __shared__ float s1[256], s2[256];
  s1[t] = a + c;
  s2[t] = a * a + c * c;
  __syncthreads();
  for (int off = 128; off > 0; off >>= 1) {
    if (t < off) { s1[t] += s1[t + off]; s2[t] += s2[t + off]; }
    __syncthreads();
  }
  float m = s1[0] * (1.0f / 512.0f);
  float var = s2[0] * (1.0f / 512.0f) - m * m;
  float r = rsqrtf(var + 1e-5f);
  out_bf[(long)row * DIMD + t] = bf16_rne((a - m) * r * g[t] + bb[t]);
  out_bf[(long)row * DIMD + t + 256] = bf16_rne((c - m) * r * g[t + 256] + bb[t + 256]);
}

// ---------------- ALL weight transposes, BOTH layers, one dispatch ----------------
// grid (3232, 2): y = layer.
__global__ void wtrans_all_kernel(const float* __restrict__ Wq, const float* __restrict__ Wk,
                                  const float* __restrict__ Wv, const float* __restrict__ Wg,
                                  const float* __restrict__ Wo, const float* __restrict__ Wkc,
                                  const float* __restrict__ Wvc, const float* __restrict__ w1,
                                  const float* __restrict__ w2,
                                  ushort* __restrict__ wqkv_t, ushort* __restrict__ wo_t,
                                  ushort* __restrict__ w1_t, ushort* __restrict__ w2_t,
                                  ushort* __restrict__ wkc_t, ushort* __restrict__ wvc_t) {
  __shared__ float tile[32][33];
  int l = blockIdx.y;
  int t = blockIdx.x;
  const float* W; ushort* Wt; int K, N, bx, by;
  if (t < 768) {
    int which = t >> 8, rr = t & 255;
    W = (which == 0 ? Wq : (which == 1 ? Wk : Wv)) + (long)l * 512 * 512;
    Wt = wqkv_t + (long)l * QKVNG * 512 + which * 512 * 512;
    K = 512; N = 512; bx = rr & 15; by = rr >> 4;
  } else if (t < 1024) {
    int rr = t - 768; W = Wo + (long)l * 512 * 512; Wt = wo_t + (long)l * 512 * 512;
    K = 512; N = 512; bx = rr & 15; by = rr >> 4;
  } else if (t < 2048) {
    int rr = t - 1024; W = w1 + (long)l * 512 * 2048; Wt = w1_t + (long)l * 2048 * 512;
    K = 512; N = 2048; bx = rr & 63; by = rr >> 6;
  } else if (t < 3072) {
    int rr = t - 2048; W = w2 + (long)l * 2048 * 512; Wt = w2_t + (long)l * 512 * 2048;
    K = 2048; N = 512; bx = rr & 15; by = rr >> 4;
  } else if (t < 3104) {
    int rr = t - 3072; W = Wg + (long)l * 512 * 24;
    Wt = wqkv_t + (long)l * QKVNG * 512 + (long)1536 * 512;
    K = 512; N = 24; bx = rr & 1; by = rr >> 1;
  } else if (t < 3168) {
    int rr = t - 3104; W = Wkc + (long)l * 1024 * 64; Wt = wkc_t + (long)l * 64 * 1024;
    K = 1024; N = 64; bx = rr & 1; by = rr >> 1;
  } else {
    int rr = t - 3168; W = Wvc + (long)l * 1024 * 64; Wt = wvc_t + (long)l * 64 * 1024;
    K = 1024; N = 64; bx = rr & 1; by = rr >> 1;
  }
  int k0 = by * 32, n0 = bx * 32;
  int tx = threadIdx.x, ty = threadIdx.y;
#pragma unroll
  for (int r = 0; r < 32; r += 8)
    tile[ty + r][tx] = (n0 + tx < N) ? W[(long)(k0 + ty + r) * N + n0 + tx] : 0.f;
  __syncthreads();
#pragma unroll
  for (int r = 0; r < 32; r += 8)
    Wt[(long)(n0 + ty + r) * K + k0 + tx] = bf16_rne(tile[tx][ty + r]);
}

// ---------------- 64x64-tile bf16 MFMA GEMM ----------------
// mode 1: Cbf = gelu(acc + bias); mode 2: qkv+gate; mode 4: split-K atomicAdd.
__global__ __launch_bounds__(256) void mfma_gemm(
    const ushort* __restrict__ A, const ushort* __restrict__ Bt,
    const float* __restrict__ bias,
    float* __restrict__ Cf, ushort* __restrict__ Cbf, float* __restrict__ gb,
    int M, int N, int K, int kSlice, int mode) {
  __shared__ short As[64][72];
  __shared__ short Bs[64][72];
  int tid = threadIdx.x;
  int lane = tid & 63, wave = tid >> 6;
  int wm = wave >> 1, wn = wave & 1;
  int rowBase = blockIdx.y * 64, colBase = blockIdx.x * 64;
  int m = lane & 15, kg = lane >> 4;
  int kBeg = blockIdx.z * kSlice;
  int kEnd = imin(K, kBeg + kSlice);
  f32x4 acc[2][2] = {};
  for (int k0 = kBeg; k0 < kEnd; k0 += 64) {
#pragma unroll
    for (int cc = 0; cc < 2; ++cc) {
      int c = tid * 2 + cc;
      int r = c >> 3, kc = c & 7;
      short8 av = {};
      int gr = rowBase + r;
      if (gr < M) av = *(const short8*)(A + (long)gr * K + k0 + kc * 8);
      *(short8*)&As[r][kc * 8] = av;
      short8 bv = *(const short8*)(Bt + (long)(colBase + r) * K + k0 + kc * 8);
      *(short8*)&Bs[r][kc * 8] = bv;
    }
    __syncthreads();
#pragma unroll
    for (int ks = 0; ks < 2; ++ks) {
      short8 a0 = *(const short8*)&As[wm * 32 + m][ks * 32 + kg * 8];
      short8 a1 = *(const short8*)&As[wm * 32 + 16 + m][ks * 32 + kg * 8];
      short8 b0 = *(const short8*)&Bs[wn * 32 + m][ks * 32 + kg * 8];
      short8 b1 = *(const short8*)&Bs[wn * 32 + 16 + m][ks * 32 + kg * 8];
      acc[0][0] = __builtin_amdgcn_mfma_f32_16x16x32_bf16(a0, b0, acc[0][0], 0, 0, 0);
      acc[0][1] = __builtin_amdgcn_mfma_f32_16x16x32_bf16(a0, b1, acc[0][1], 0, 0, 0);
      acc[1][0] = __builtin_amdgcn_mfma_f32_16x16x32_bf16(a1, b0, acc[1][0], 0, 0, 0);
      acc[1][1] = __builtin_amdgcn_mfma_f32_16x16x32_bf16(a1, b1, acc[1][1], 0, 0, 0);
    }
    __syncthreads();
  }
#pragma unroll
  for (int mt = 0; mt < 2; ++mt)
#pragma unroll
    for (int nt = 0; nt < 2; ++nt) {
      int col = colBase + wn * 32 + nt * 16 + m;
#pragma unroll
      for (int r = 0; r < 4; ++r) {
        int row = rowBase + wm * 32 + mt * 16 + kg * 4 + r;
        if (row >= M) continue;
        float v = acc[mt][nt][r];
        if (mode == 2) {
          if (col < QKVN) Cbf[(long)row * QKVN + col] = bf16_rne(v);
          else if (col < QKVNG) gb[(long)row * 64 + (col - QKVN)] = 1.f / (1.f + __expf(-v));
        } else if (mode == 1) {
          v += bias[col];
          float u = 0.7978845608028654f * (v + 0.044715f * v * v * v);
          v = 0.5f * v * (1.f + tanhf(u));
          Cbf[(long)row * N + col] = bf16_rne(v);
        } else {  // mode 4
          if (bias && blockIdx.z == 0) v += bias[col];
          atomicAdd(&Cf[(long)row * N + col], v);
        }
      }
    }
}

// ---------------- ck (z=0) + cv-transposed-into-Vt (z=1), one dispatch ----------------
// z=0: ckb[row][d] = kwm[row] . wkc[d]          (row tile = blockIdx.y)
// z=1: Vt[z16*64+d][640+j] = vwm[col] . wvc[d]  (col tile = blockIdx.y; coalesced)
__global__ __launch_bounds__(256) void ckcv_gemm(
    const ushort* __restrict__ kwm, const ushort* __restrict__ vwm,
    const ushort* __restrict__ wkc_t, const ushort* __restrict__ wvc_t,
    ushort* __restrict__ ckb, ushort* __restrict__ Vt) {
  const int K = 1024;
  bool cvpath = blockIdx.z != 0;
  const ushort* A  = cvpath ? wvc_t : kwm;
  const ushort* Bt = cvpath ? vwm : wkc_t;
  int rowBase = cvpath ? 0 : blockIdx.y * 64;
  int colBase = cvpath ? blockIdx.y * 64 : 0;
  int aRows = cvpath ? 64 : MCKD;
  int bRows = cvpath ? MCKD : 64;
  __shared__ short As[64][72];
  __shared__ short Bs[64][72];
  int tid = threadIdx.x;
  int lane = tid & 63, wave = tid >> 6;
  int wm = wave >> 1, wn = wave & 1;
  int m = lane & 15, kg = lane >> 4;
  f32x4 acc[2][2] = {};
  for (int k0 = 0; k0 < K; k0 += 64) {
#pragma unroll
    for (int cc = 0; cc < 2; ++cc) {
      int c = tid * 2 + cc;
      int r = c >> 3, kc = c & 7;
      short8 av = {};
      if (rowBase + r < aRows) av = *(const short8*)(A + (long)(rowBase + r) * K + k0 + kc * 8);
      *(short8*)&As[r][kc * 8] = av;
      short8 bv = {};
      if (colBase + r < bRows) bv = *(const short8*)(Bt + (long)(colBase + r) * K + k0 + kc * 8);
      *(short8*)&Bs[r][kc * 8] = bv;
    }
    __syncthreads();
#pragma unroll
    for (int ks = 0; ks < 2; ++ks) {
      short8 a0 = *(const short8*)&As[wm * 32 + m][ks * 32 + kg * 8];
      short8 a1 = *(const short8*)&As[wm * 32 + 16 + m][ks * 32 + kg * 8];
      short8 b0 = *(const short8*)&Bs[wn * 32 + m][ks * 32 + kg * 8];
      short8 b1 = *(const short8*)&Bs[wn * 32 + 16 + m][ks * 32 + kg * 8];
      acc[0][0] = __builtin_amdgcn_mfma_f32_16x16x32_bf16(a0, b0, acc[0][0], 0, 0, 0);
      acc[0][1] = __builtin_amdgcn_mfma_f32_16x16x32_bf16(a0, b1, acc[0][1], 0, 0, 0);
      acc[1][0] = __builtin_amdgcn_mfma_f32_16x16x32_bf16(a1, b0, acc[1][0], 0, 0, 0);
      acc[1][1] = __builtin_amdgcn_mfma_f32_16x16x32_bf16(a1, b1, acc[1][1], 0, 0, 0);
    }
    __syncthreads();
  }
#pragma unroll
  for (int mt = 0; mt < 2; ++mt)
#pragma unroll
    for (int nt = 0; nt < 2; ++nt) {
      int col = colBase + wn * 32 + nt * 16 + m;
#pragma unroll
      for (int r = 0; r < 4; ++r) {
        int row = rowBase + wm * 32 + mt * 16 + kg * 4 + r;
        float v = acc[mt][nt][r];
        if (!cvpath) {
          if (row < MCKD) ckb[(long)row * DHD + col] = bf16_rne(v);
        } else {
          if (col < MCKD) {
            int z16 = col / NC, j = col - z16 * NC;
            Vt[((long)z16 * 64 + row) * PSTRIDE + 640 + j] = bf16_rne(v);
          }
        }
      }
    }
}

// ---------------- batched score GEMM: merged dense (x<10) + compressed (x>=10) ----------------
__global__ __launch_bounds__(256) void score_kernel(
    const ushort* __restrict__ qkv_bf, const ushort* __restrict__ ckb,
    ushort* __restrict__ Sf, ushort* __restrict__ Scb, float scale) {
  __shared__ short As[64][72];
  __shared__ short Bs[64][72];
  int z = blockIdx.z;
  int b = z >> 3, h = z & 7;
  int i0 = blockIdx.y * 64;
  int xb = blockIdx.x;
  bool isC = xb >= 10;
  int j0 = (isC ? (xb - 10) : xb) * 64;
  int tid = threadIdx.x;
  int lane = tid & 63, wave = tid >> 6;
  int wm = wave >> 1, wn = wave & 1;
  const ushort* aBase = qkv_bf + (long)b * NTOK * QKVN + h * 64;
  const ushort* bBase = aBase + 512;
  const ushort* cBase = ckb + (long)z * NC * DHD;
#pragma unroll
  for (int rep = 0; rep < 4; ++rep) {
    int row = rep * 16 + (tid >> 4);
    int c4 = tid & 15;
    int gi = i0 + row;
    short4v a16 = {};
    if (gi < NTOK) a16 = *(const short4v*)(aBase + (long)gi * QKVN + c4 * 4);
    *(short4v*)&As[row][c4 * 4] = a16;
    int gj = j0 + row;
    short4v b16 = {};
    if (isC) {
      if (gj < NC) b16 = *(const short4v*)(cBase + (long)gj * DHD + c4 * 4);
    } else {
      if (gj < NTOK) b16 = *(const short4v*)(bBase + (long)gj * QKVN + c4 * 4);
    }
    *(short4v*)&Bs[row][c4 * 4] = b16;
  }
  __syncthreads();
  int m = lane & 15, kg = lane >> 4;
  f32x4 acc[2][2] = {};
#pragma unroll
  for (int ks = 0; ks < 2; ++ks) {
    short8 a0 = *(const short8*)&As[wm * 32 + m][ks * 32 + kg * 8];
    short8 a1 = *(const short8*)&As[wm * 32 + 16 + m][ks * 32 + kg * 8];
    short8 b0 = *(const short8*)&Bs[wn * 32 + m][ks * 32 + kg * 8];
    short8 b1 = *(const short8*)&Bs[wn * 32 + 16 + m][ks * 32 + kg * 8];
    acc[0][0] = __builtin_amdgcn_mfma_f32_16x16x32_bf16(a0, b0, acc[0][0], 0, 0, 0);
    acc[0][1] = __builtin_amdgcn_mfma_f32_16x16x32_bf16(a0, b1, acc[0][1], 0, 0, 0);
    acc[1][0] = __builtin_amdgcn_mfma_f32_16x16x32_bf16(a1, b0, acc[1][0], 0, 0, 0);
    acc[1][1] = __builtin_amdgcn_mfma_f32_16x16x32_bf16(a1, b1, acc[1][1], 0, 0, 0);
  }
  int nvalid = isC ? NC : NTOK;
  int sstride = isC ? SCSTRIDE : SFSTRIDE;
  ushort* Sz = (isC ? Scb : Sf) + (long)z * NTOK * sstride;
#pragma unroll
  for (int mt = 0; mt < 2; ++mt)
#pragma unroll
    for (int nt = 0; nt < 2; ++nt) {
      int col = j0 + wn * 32 + nt * 16 + m;
#pragma unroll
      for (int r = 0; r < 4; ++r) {
        int row = i0 + wm * 32 + mt * 16 + kg * 4 + r;
        if (row < NTOK && col < nvalid)
          Sz[(long)row * sstride + col] = bf16_rne(acc[mt][nt][r] * scale);
      }
    }
}

// ---------------- kw/vw build + Vt V-part (merged; block-range decode) ----------------
__global__ void kwvt_kernel(const ushort* __restrict__ qkv_bf,
                            const float* __restrict__ kpe, const float* __restrict__ vpe,
                            ushort* __restrict__ kwm, ushort* __restrict__ vwm,
                            ushort* __restrict__ Vt) {
  __shared__ short tile[64][72];
  int bid = blockIdx.x;
  if (bid < MCKD) {
    // kw/vw build
    int j = bid % NC;
    int bh = bid / NC;
    int h = bh & 7, b = bh >> 3;
    int t = threadIdx.x >> 4;
    int d4 = threadIdx.x & 15;
    int tok = j * CSD + t;
    float k0 = 0.f, k1 = 0.f, k2 = 0.f, k3 = 0.f, v0 = 0.f, v1 = 0.f, v2 = 0.f, v3 = 0.f;
    if (tok < NTOK) {
      const ushort* base = qkv_bf + (long)(b * NTOK + tok) * QKVN + h * DHD + d4 * 4;
      short4v kv = *(const short4v*)(base + 512);
      short4v vv = *(const short4v*)(base + 1024);
      k0 = bf16_to_f((ushort)kv.x); k1 = bf16_to_f((ushort)kv.y);
      k2 = bf16_to_f((ushort)kv.z); k3 = bf16_to_f((ushort)kv.w);
      v0 = bf16_to_f((ushort)vv.x); v1 = bf16_to_f((ushort)vv.y);
      v2 = bf16_to_f((ushort)vv.z); v3 = bf16_to_f((ushort)vv.w);
    }
    float4 kp = *(const float4*)(kpe + t * DHD + d4 * 4);
    float4 vp = *(const float4*)(vpe + t * DHD + d4 * 4);
    short4v ko, vo;
    ko.x = (short)bf16_rne(k0 + kp.x); ko.y = (short)bf16_rne(k1 + kp.y);
    ko.z = (short)bf16_rne(k2 + kp.z); ko.w = (short)bf16_rne(k3 + kp.w);
    vo.x = (short)bf16_rne(v0 + vp.x); vo.y = (short)bf16_rne(v1 + vp.y);
    vo.z = (short)bf16_rne(v2 + vp.z); vo.w = (short)bf16_rne(v3 + vp.w);
    long ob = (long)bid * 1024 + t * DHD + d4 * 4;
    *(short4v*)(kwm + ob) = ko;
    *(short4v*)(vwm + ob) = vo;
  } else {
    // Vt V-part: transpose 64x64 token-block of V into Vt[z][d][kt*64..]
    int t = bid - MCKD;      // 0..159
    int kt = t % 10, z = t / 10;
    int b = z >> 3, h = z & 7;
    int tid = threadIdx.x;
    int r = tid >> 2, seg = tid & 3;
    short8 a0 = {}, a1 = {};
    int tok = kt * 64 + r;
    if (tok < NTOK) {
      const ushort* src = qkv_bf + (long)(b * NTOK + tok) * QKVN + 1024 + h * 64 + seg * 16;
      a0 = *(const short8*)src;
      a1 = *(const short8*)(src + 8);
    }
    *(short8*)&tile[r][seg * 16] = a0;
    *(short8*)&tile[r][seg * 16 + 8] = a1;
    __syncthreads();
    int d = tid >> 2;
    short8 o0, o1;
#pragma unroll
    for (int q = 0; q < 8; ++q) o0[q] = tile[seg * 16 + q][d];
#pragma unroll
    for (int q = 0; q < 8; ++q) o1[q] = tile[seg * 16 + 8 + q][d];
    ushort* dst = Vt + ((long)z * 64 + d) * PSTRIDE + kt * 64 + seg * 16;
    *(short8*)dst = o0;
    *(short8*)(dst + 8) = o1;
  }
}

// ---------------- prob: softmax + top-k + gates -> dense gated P row ----------------
__global__ __launch_bounds__(256, 4) void prob_kernel(
    const ushort* __restrict__ Sf, const ushort* __restrict__ Scb,
    const float* __restrict__ gb, ushort* __restrict__ P) {
  int qt = blockIdx.x % NC;
  int z = blockIdx.x / NC;
  int h = z & 7, b = z >> 3;
  int tid = threadIdx.x, lane = tid & 63, w = tid >> 6;
  int i0 = qt * 4 + w;
  bool valid = i0 < NTOK;
  int i = imin(i0, NTOK - 1);

  __shared__ float scL[4][192];
  __shared__ float ssL[4][256];
  __shared__ float swL[4][32];
  __shared__ float impL[4][16];
  __shared__ int selL[4][KSELD];
  float* sc = scL[w]; float* ss = ssL[w];
  float* swv = swL[w]; float* imp = impL[w]; int* sel = selL[w];

  const ushort* scRow = Scb + ((long)z * NTOK + i) * SCSTRIDE;
  const ushort* sfRow = Sf + ((long)z * NTOK + i) * SFSTRIDE;

  float e[3], mC = -1e30f;
#pragma unroll
  for (int c = 0; c < 3; ++c) {
    int j = c * 64 + lane;
    float s = bf16_to_f(scRow[imin(j, NC - 1)]);
    s = (j < NC) ? s : -1e30f;
    e[c] = s;
    mC = fmaxf(mC, s);
  }
#pragma unroll
  for (int msk = 1; msk < 64; msk <<= 1) mC = fmaxf(mC, __shfl_xor(mC, msk, 64));
  float sumC = 0.f;
#pragma unroll
  for (int c = 0; c < 3; ++c) {
    float ev = (e[c] > -1e29f) ? __expf(e[c] - mC) : 0.f;
    sc[c * 64 + lane] = ev;
    sumC += ev;
  }
#pragma unroll
  for (int msk = 1; msk < 64; msk <<= 1) sumC += __shfl_xor(sumC, msk, 64);
  __syncthreads();

  if (lane < NSB) {
    int lo = imax(0, 16 * lane - 2), hi = imin(NC - 1, 16 * lane + 13);
    float s = 0.f;
    for (int j = lo; j <= hi; ++j) s += sc[j];
    imp[lane] = s;
  }
  __syncthreads();
  if (lane == 0) {
    unsigned used = 0;
    for (int r = 0; r < KSELD; ++r) {
      int bi = 0; float bv = -1e30f;
      for (int s = 0; s < NSB; ++s)
        if (!((used >> s) & 1u) && imp[s] > bv) { bv = imp[s]; bi = s; }
      used |= 1u << bi;
      sel[r] = bi;
    }
  }
  __syncthreads();

  float es[4], mS = -1e30f;
#pragma unroll
  for (int c = 0; c < 4; ++c) {
    int tok = sel[c] * SBD + lane;
    float s = bf16_to_f(sfRow[imin(tok, NTOK - 1)]);
    s = (tok < NTOK) ? s : -1e30f;
    es[c] = s;
    mS = fmaxf(mS, s);
  }
#pragma unroll
  for (int msk = 1; msk < 64; msk <<= 1) mS = fmaxf(mS, __shfl_xor(mS, msk, 64));
  float sumS = 0.f;
#pragma unroll
  for (int c = 0; c < 4; ++c) {
    float ev = (es[c] > -1e29f) ? __expf(es[c] - mS) : 0.f;
    ss[c * 64 + lane] = ev;
    sumS += ev;
  }
#pragma unroll
  for (int msk = 1; msk < 64; msk <<= 1) sumS += __shfl_xor(sumS, msk, 64);

  float sw_s;
  {
    int pos = i + (lane & 31) - SWD / 2;
    float s = bf16_to_f(sfRow[imin(imax(pos, 0), NTOK - 1)]);
    sw_s = (pos >= 0 && pos < NTOK) ? s : -1e30f;
  }
  float mW = sw_s;
#pragma unroll
  for (int msk = 1; msk < 32; msk <<= 1) mW = fmaxf(mW, __shfl_xor(mW, msk, 64));
  float ew = (sw_s > -1e29f) ? __expf(sw_s - mW) : 0.f;
  float sumW = ew;
#pragma unroll
  for (int msk = 1; msk < 32; msk <<= 1) sumW += __shfl_xor(sumW, msk, 64);
  if (lane < SWD) swv[lane] = ew;
  __syncthreads();

  if (!valid) return;
  const float* gp = gb + (long)(b * NTOK + i) * 64 + h * 3;
  float rC = gp[0] / sumC, rS = gp[1] / sumS, rW = gp[2] / sumW;
  ushort* prow = P + ((long)z * NTOK + i0) * PSTRIDE;
#pragma unroll
  for (int c = 0; c < 10; ++c) {
    int col = c * 64 + lane;
    float val = 0.f;
#pragma unroll
    for (int r = 0; r < 4; ++r)
      if (sel[r] == c) val += rS * ss[r * 64 + lane];
    int t = col - i + 16;
    if (t >= 0 && t < SWD && col < NTOK) val += rW * swv[t];
    prow[col] = bf16_rne(val);
  }
#pragma unroll
  for (int c = 0; c < 3; ++c) {
    int j = c * 64 + lane;
    float val = (j < NC) ? rC * sc[j] : 0.f;
    prow[640 + j] = bf16_rne(val);
  }
}

// ---------------- PV GEMM: comb[b,i,h*64+d] = P[z] @ Vext[z] ----------------
__global__ __launch_bounds__(256) void pv_gemm(const ushort* __restrict__ P,
                                               const ushort* __restrict__ Vt,
                                               ushort* __restrict__ comb) {
  __shared__ short As[64][72];
  __shared__ short Bs[64][72];
  int z = blockIdx.y;
  int b = z >> 3, h = z & 7;
  int rowBase = blockIdx.x * 64;
  int tid = threadIdx.x;
  int lane = tid & 63, wave = tid >> 6;
  int wm = wave >> 1, wn = wave & 1;
  const ushort* Pz = P + (long)z * NTOK * PSTRIDE;
  const ushort* Vz = Vt + (long)z * 64 * PSTRIDE;
  int m = lane & 15, kg = lane >> 4;
  f32x4 acc[2][2] = {};
  for (int k0 = 0; k0 < PSTRIDE; k0 += 64) {
#pragma unroll
    for (int cc = 0; cc < 2; ++cc) {
      int c = tid * 2 + cc;
      int r = c >> 3, kc = c & 7;
      short8 av = {};
      int gr = rowBase + r;
      if (gr < NTOK) av = *(const short8*)(Pz + (long)gr * PSTRIDE + k0 + kc * 8);
      *(short8*)&As[r][kc * 8] = av;
      short8 bv = *(const short8*)(Vz + (long)r * PSTRIDE + k0 + kc * 8);
      *(short8*)&Bs[r][kc * 8] = bv;
    }
    __syncthreads();
#pragma unroll
    for (int ks = 0; ks < 2; ++ks) {
      short8 a0 = *(const short8*)&As[wm * 32 + m][ks * 32 + kg * 8];
      short8 a1 = *(const short8*)&As[wm * 32 + 16 + m][ks * 32 + kg * 8];
      short8 b0 = *(const short8*)&Bs[wn * 32 + m][ks * 32 + kg * 8];
      short8 b1 = *(const short8*)&Bs[wn * 32 + 16 + m][ks * 32 + kg * 8];
      acc[0][0] = __builtin_amdgcn_mfma_f32_16x16x32_bf16(a0, b0, acc[0][0], 0, 0, 0);
      acc[0][1] = __builtin_amdgcn_mfma_f32_16x16x32_bf16(a0, b1, acc[0][1], 0, 0, 0);
      acc[1][0] = __builtin_amdgcn_mfma_f32_16x16x32_bf16(a1, b0, acc[1][0], 0, 0, 0);
      acc[1][1] = __builtin_amdgcn_mfma_f32_16x16x32_bf16(a1, b1, acc[1][1], 0, 0, 0);
    }
    __syncthreads();
  }
#pragma unroll
  for (int mt = 0; mt < 2; ++mt)
#pragma unroll
    for (int nt = 0; nt < 2; ++nt) {
      int col = wn * 32 + nt * 16 + m;
#pragma unroll
      for (int r = 0; r < 4; ++r) {
        int row = rowBase + wm * 32 + mt * 16 + kg * 4 + r;
        if (row < NTOK)
          comb[(long)(b * NTOK + row) * DIMD + h * 64 + col] = bf16_rne(acc[mt][nt][r]);
      }
    }
}

// ---------------- head with fused final LN: grid (16, BATCH), 256 thr ----------------
__global__ void head_kernel(const float* __restrict__ x, const float* __restrict__ hg,
                            const float* __restrict__ hb, const float* __restrict__ W,
                            const float* __restrict__ bias, float* __restrict__ out) {
  int b = blockIdx.y;
  int tid = threadIdx.x;
  const float* xr = x + (long)b * NTOK * DIMD;  // token 0 of batch b
  __shared__ float red1[256], red2[256];
  float a = xr[tid], c = xr[tid + 256];
  red1[tid] = a + c;
  red2[tid] = a * a + c * c;
  __syncthreads();
  for (int off = 128; off > 0; off >>= 1) {
    if (tid < off) { red1[tid] += red1[tid + off]; red2[tid] += red2[tid + off]; }
    __syncthreads();
  }
  float m = red1[0] * (1.f / 512.f);
  float var = red2[0] * (1.f / 512.f) - m * m;
  float rs = rsqrtf(var + 1e-5f);
  __shared__ float hs[512];
  hs[tid] = (a - m) * rs * hg[tid] + hb[tid];
  hs[tid + 256] = (c - m) * rs * hg[tid + 256] + hb[tid + 256];
  __syncthreads();
  int col = blockIdx.x * 64 + (tid & 63);
  int ks = tid >> 6;  // 0..3, K-slices of 128
  float acc = 0.f;
  if (col < NCLSD) {
    for (int k = ks * 128; k < ks * 128 + 128; ++k)
      acc += hs[k] * W[(long)k * NCLSD + col];
  }
  __shared__ float part[4][64];
  part[ks][tid & 63] = acc;
  __syncthreads();
  if (tid < 64) {
    int c2 = blockIdx.x * 64 + tid;
    if (c2 < NCLSD)
      out[b * NCLSD + c2] = part[0][tid] + part[1][tid] + part[2][tid] + part[3][tid] + bias[c2];
  }
}

extern "C" void kernel_launch(void* const* d_in, const int* in_sizes, int n_in,
                              void* d_out, int out_size, void* d_ws, size_t ws_size,
                              hipStream_t stream) {
  const float* img     = (const float*)d_in[0];
  const float* patch_w = (const float*)d_in[1];
  const float* patch_b = (const float*)d_in[2];
  const float* pos_emb = (const float*)d_in[3];
  const float* cls_tok = (const float*)d_in[4];
  const float* ln1_g   = (const float*)d_in[5];
  const float* ln1_b   = (const float*)d_in[6];
  const float* Wq      = (const float*)d_in[7];
  const float* Wk      = (const float*)d_in[8];
  const float* Wv      = (const float*)d_in[9];
  const float* Wg      = (const float*)d_in[10];
  const float* Wo      = (const float*)d_in[11];
  const float* kpe     = (const float*)d_in[12];
  const float* vpe     = (const float*)d_in[13];
  const float* Wkc     = (const float*)d_in[14];
  const float* Wvc     = (const float*)d_in[15];
  const float* ln2_g   = (const float*)d_in[16];
  const float* ln2_b   = (const float*)d_in[17];
  const float* ff_w1   = (const float*)d_in[18];
  const float* ff_b1   = (const float*)d_in[19];
  const float* ff_w2   = (const float*)d_in[20];
  const float* ff_b2   = (const float*)d_in[21];
  const float* hln_g   = (const float*)d_in[22];
  const float* hln_b   = (const float*)d_in[23];
  const float* head_w  = (const float*)d_in[24];
  const float* head_b  = (const float*)d_in[25];
  float* out = (float*)d_out;

  // ---- workspace carve (~54 MB; ws is 256 MB) ----
  char* p = (char*)d_ws;
  const long MROW = (long)BATCH * NTOK;            // 1154
  float* x       = (float*)p;  p += MROW * DIMD * 4;
  ushort* qkv_bf = (ushort*)p; p += MROW * QKVN * 2;
  ushort* h_bf   = (ushort*)p; p += MROW * DIMD * 2;
  ushort* comb_bf= (ushort*)p; p += MROW * DIMD * 2;
  float* gb      = (float*)p;  p += MROW * 64 * 4;
  ushort* ckb    = (ushort*)p; p += (long)MCKD * DHD * 2;
  ushort* Vt     = (ushort*)p; p += (long)BATCH * NH * 64 * PSTRIDE * 2;
  ushort* Scb    = (ushort*)p; p += (long)BATCH * NH * NTOK * SCSTRIDE * 2;
  // per-layer weight buffers (both layers live)
  ushort* wqkv_t = (ushort*)p; p += 2L * QKVNG * DIMD * 2;
  ushort* wo_t   = (ushort*)p; p += 2L * DIMD * DIMD * 2;
  ushort* w1_t   = (ushort*)p; p += 2L * MLPD * DIMD * 2;
  ushort* w2_t   = (ushort*)p; p += 2L * DIMD * MLPD * 2;
  ushort* wkc_t  = (ushort*)p; p += 2L * 64 * 1024 * 2;
  ushort* wvc_t  = (ushort*)p; p += 2L * 64 * 1024 * 2;
  // region A: kwm+vwm aliased with P (disjoint lifetimes)
  ushort* kwm    = (ushort*)p;
  ushort* vwm    = kwm + (long)MCKD * 1024;
  ushort* P      = kwm;
  p += (long)BATCH * NH * NTOK * PSTRIDE * 2;
  // region B: Sf aliased with ff1_bf (disjoint lifetimes)
  ushort* Sf     = (ushort*)p;
  ushort* ff1_bf = Sf;
  p += (long)BATCH * NH * NTOK * SFSTRIDE * 2;

  const int M = (int)MROW;                  // 1154
  const int MB64 = (M + 63) / 64;           // 19
  const float scale = 0.125f;
  dim3 thrT(32, 8);

  patch_kernel<<<(M * DIMD + 255) / 256, 256, 0, stream>>>(img, patch_w, patch_b, pos_emb, cls_tok, x);
  // both layers' weight transposes, one dispatch
  wtrans_all_kernel<<<dim3(3232, 2), thrT, 0, stream>>>(Wq, Wk, Wv, Wg, Wo, Wkc, Wvc,
                                                        ff_w1, ff_w2, wqkv_t, wo_t, w1_t, w2_t,
                                                        wkc_t, wvc_t);

  for (int l = 0; l < 2; ++l) {
    const ushort* wqkv_l = wqkv_t + (long)l * QKVNG * DIMD;
    const ushort* wo_l   = wo_t + (long)l * DIMD * DIMD;
    const ushort* w1t_l  = w1_t + (long)l * MLPD * DIMD;
    const ushort* w2t_l  = w2_t + (long)l * DIMD * MLPD;
    const ushort* wkc_l  = wkc_t + (long)l * 64 * 1024;
    const ushort* wvc_l  = wvc_t + (long)l * 64 * 1024;
    const float* kpe_l = kpe + (long)l * CBD * DHD;
    const float* vpe_l = vpe + (long)l * CBD * DHD;
    const float* b1_l  = ff_b1 + (long)l * MLPD;
    const float* b2_l  = ff_b2 + (long)l * DIMD;

    // h = LN1(x) -> bf16
    ln_kernel<<<M, 256, 0, stream>>>(x, ln1_g + (long)l * DIMD, ln1_b + (long)l * DIMD, h_bf);
    // qkv (+gate) = h @ [Wq|Wk|Wv|Wg]   (mode 2)
    mfma_gemm<<<dim3(QKVNG / 64, MB64), 256, 0, stream>>>(h_bf, wqkv_l, nullptr, nullptr, qkv_bf, gb, M, QKVNG, DIMD, DIMD, 2);
    // kw/vw build + Vt V-part (merged)
    kwvt_kernel<<<MCKD + 160, 256, 0, stream>>>(qkv_bf, kpe_l, vpe_l, kwm, vwm, Vt);
    // ck GEMM + cv-transposed-into-Vt GEMM (one dispatch)
    ckcv_gemm<<<dim3(1, (MCKD + 63) / 64, 2), 256, 0, stream>>>(kwm, vwm, wkc_l, wvc_l, ckb, Vt);
    // merged dense + compressed score GEMMs
    score_kernel<<<dim3(13, 10, BATCH * NH), 256, 0, stream>>>(qkv_bf, ckb, Sf, Scb, scale);
    // gated probability rows
    prob_kernel<<<BATCH * NH * NC, 256, 0, stream>>>(Sf, Scb, gb, P);
    // comb = P @ Vext
    pv_gemm<<<dim3(10, BATCH * NH), 256, 0, stream>>>(P, Vt, comb_bf);
    // x += comb @ Wo   (mode 4, split-K=2)
    mfma_gemm<<<dim3(DIMD / 64, MB64, 2), 256, 0, stream>>>(comb_bf, wo_l, nullptr, x, nullptr, nullptr, M, DIMD, DIMD, 256, 4);
    // h = LN2(x) -> bf16
    ln_kernel<<<M, 256, 0, stream>>>(x, ln2_g + (long)l * DIMD, ln2_b + (long)l * DIMD, h_bf);
    // ff1 = gelu(h @ W1 + b1) -> bf16  (mode 1)
    mfma_gemm<<<dim3(MLPD / 64, MB64), 256, 0, stream>>>(h_bf, w1t_l, b1_l, nullptr, ff1_bf, nullptr, M, MLPD, DIMD, DIMD, 1);
    // x += ff1 @ W2 + b2   (mode 4, split-K=4)
    mfma_gemm<<<dim3(DIMD / 64, MB64, 4), 256, 0, stream>>>(ff1_bf, w2t_l, b2_l, x, nullptr, nullptr, M, DIMD, MLPD, 512, 4);
  }

  // head with fused final LN
  head_kernel<<<dim3(16, BATCH), 256, 0, stream>>>(x, hln_g, hln_b, head_w, head_b, out);
}

// Round 9
// 364.745 us; speedup vs baseline: 1.8597x; 1.0402x over previous
//
#include <hip/hip_runtime.h>
#include <math.h>

// SparseViT forward. Round 9: mfma_gemm staging via __builtin_amdgcn_global_load_lds
// (width=16, XOR-swizzled unpadded LDS tiles, conflict-free b128 fragment reads);
// patch embed merged into the wtrans dispatch. Other kernels unchanged from R8.
// B=2, N=577, DIM=512, H=8, DH=64, DEPTH=2, MLP=2048, NCLS=1000, nc=145, ns=10

#define NTOK 577
#define DIMD 512
#define NH 8
#define DHD 64
#define NC 145
#define NSB 10
#define KSELD 4
#define SBD 64
#define CBD 16
#define CSD 4
#define SWD 32
#define MLPD 2048
#define NCLSD 1000
#define BATCH 2
#define QKVN 1536    // q|k|v columns (output stride)
#define QKVNG 1600   // + 64 gate cols
#define SFSTRIDE 592
#define SCSTRIDE 160
#define PSTRIDE 832  // 640 token cols + 192 compressed cols
#define MCKD 2320    // BATCH*NH*NC

typedef unsigned short ushort;
typedef __attribute__((ext_vector_type(8))) short short8;
typedef __attribute__((ext_vector_type(4))) short short4v;
typedef __attribute__((ext_vector_type(4))) float f32x4;

#if defined(__has_builtin)
#if __has_builtin(__builtin_amdgcn_global_load_lds)
#define HAVE_GLL 1
#endif
#endif

#ifdef HAVE_GLL
__device__ __forceinline__ void gll16(const ushort* g, short* l) {
  __builtin_amdgcn_global_load_lds(
      (const __attribute__((address_space(1))) unsigned int*)g,
      (__attribute__((address_space(3))) unsigned int*)l, 16, 0, 0);
}
#endif

__device__ __forceinline__ ushort bf16_rne(float f) {
  union { float f; unsigned u; } v; v.f = f;
  unsigned u = v.u;
  unsigned r = (u + 0x7fffu + ((u >> 16) & 1u)) >> 16;
  return (ushort)r;
}
__device__ __forceinline__ float bf16_to_f(ushort s) {
  union { unsigned u; float f; } v; v.u = ((unsigned)s) << 16;
  return v.f;
}
__device__ __forceinline__ int imin(int a, int b) { return a < b ? a : b; }
__device__ __forceinline__ int imax(int a, int b) { return a > b ? a : b; }

// ---------------- merged prep: wtrans (both layers, bid<6464) + patch embed ----------------
__global__ void prep_kernel(const float* __restrict__ Wq, const float* __restrict__ Wk,
                            const float* __restrict__ Wv, const float* __restrict__ Wg,
                            const float* __restrict__ Wo, const float* __restrict__ Wkc,
                            const float* __restrict__ Wvc, const float* __restrict__ w1,
                            const float* __restrict__ w2,
                            ushort* __restrict__ wqkv_t, ushort* __restrict__ wo_t,
                            ushort* __restrict__ w1_t, ushort* __restrict__ w2_t,
                            ushort* __restrict__ wkc_t, ushort* __restrict__ wvc_t,
                            const float* __restrict__ img, const float* __restrict__ pw,
                            const float* __restrict__ pb, const float* __restrict__ pos,
                            const float* __restrict__ cls, float* __restrict__ x) {
  int bid = blockIdx.x;
  int tid = threadIdx.x;
  if (bid >= 6464) {
    // ---- patch embed ----
    int idx = (bid - 6464) * 256 + tid;
    const int total = BATCH * NTOK * DIMD;
    if (idx >= total) return;
    int d = idx & (DIMD - 1);
    int i = (idx / DIMD) % NTOK;
    int b = idx / (DIMD * NTOK);
    float val;
    if (i == 0) {
      val = cls[d];
    } else {
      int p = i - 1;
      val = pb[d];
#pragma unroll
      for (int c = 0; c < 3; ++c)
        val += img[b * 3 * 576 + c * 576 + p] * pw[c * DIMD + d];
    }
    x[idx] = val + pos[i * DIMD + d];
    return;
  }
  // ---- weight transpose ----
  __shared__ float tile[32][33];
  int l = bid / 3232;
  int t = bid % 3232;
  const float* W; ushort* Wt; int K, N, bx, by;
  if (t < 768) {
    int which = t >> 8, rr = t & 255;
    W = (which == 0 ? Wq : (which == 1 ? Wk : Wv)) + (long)l * 512 * 512;
    Wt = wqkv_t + (long)l * QKVNG * 512 + which * 512 * 512;
    K = 512; N = 512; bx = rr & 15; by = rr >> 4;
  } else if (t < 1024) {
    int rr = t - 768; W = Wo + (long)l * 512 * 512; Wt = wo_t + (long)l * 512 * 512;
    K = 512; N = 512; bx = rr & 15; by = rr >> 4;
  } else if (t < 2048) {
    int rr = t - 1024; W = w1 + (long)l * 512 * 2048; Wt = w1_t + (long)l * 2048 * 512;
    K = 512; N = 2048; bx = rr & 63; by = rr >> 6;
  } else if (t < 3072) {
    int rr = t - 2048; W = w2 + (long)l * 2048 * 512; Wt = w2_t + (long)l * 512 * 2048;
    K = 2048; N = 512; bx = rr & 15; by = rr >> 4;
  } else if (t < 3104) {
    int rr = t - 3072; W = Wg + (long)l * 512 * 24;
    Wt = wqkv_t + (long)l * QKVNG * 512 + (long)1536 * 512;
    K = 512; N = 24; bx = rr & 1; by = rr >> 1;
  } else if (t < 3168) {
    int rr = t - 3104; W = Wkc + (long)l * 1024 * 64; Wt = wkc_t + (long)l * 64 * 1024;
    K = 1024; N = 64; bx = rr & 1; by = rr >> 1;
  } else {
    int rr = t - 3168; W = Wvc + (long)l * 1024 * 64; Wt = wvc_t + (long)l * 64 * 1024;
    K = 1024; N = 64; bx = rr & 1; by = rr >> 1;
  }
  int k0 = by * 32, n0 = bx * 32;
  int tx = tid & 31, ty = tid >> 5;
#pragma unroll
  for (int r = 0; r < 32; r += 8)
    tile[ty + r][tx] = (n0 + tx < N) ? W[(long)(k0 + ty + r) * N + n0 + tx] : 0.f;
  __syncthreads();
#pragma unroll
  for (int r = 0; r < 32; r += 8)
    Wt[(long)(n0 + ty + r) * K + k0 + tx] = bf16_rne(tile[tx][ty + r]);
}

// ---------------- layernorm ----------------
__global__ void ln_kernel(const float* __restrict__ x, const float* __restrict__ g,
                          const float* __restrict__ bb, ushort* __restrict__ out_bf) {
  int row = blockIdx.x;
  const float* xr = x + (long)row * DIMD;
  int t = threadIdx.x;
  float a = xr[t], c = xr[t + 256];
  __shared__ float s1[256], s2[256];
  s1[t] = a + c;
  s2[t] = a * a + c * c;
  __syncthreads();
  for (int off = 128; off > 0; off >>= 1) {
    if (t < off) { s1[t] += s1[t + off]; s2[t] += s2[t + off]; }
    __syncthreads();
  }
  float m = s1[0] * (1.0f / 512.0f);
  float var = s2[0] * (1.0f / 512.0f) - m * m;
  float r = rsqrtf(var + 1e-5f);
  out_bf[(long)row * DIMD + t] = bf16_rne((a - m) * r * g[t] + bb[t]);
  out_bf[(long)row * DIMD + t + 256] = bf16_rne((c - m) * r * g[t + 256] + bb[t + 256]);
}

// ---------------- 64x64-tile bf16 MFMA GEMM, global_load_lds staging ----------------
// mode 1: Cbf = gelu(acc + bias); mode 2: qkv+gate; mode 4: split-K atomicAdd.
// NOTE (GLL path): A-tile OOB rows (row>=M) are loaded unconditionally — they read
// workspace-interior bytes (all A buffers are interior to d_ws) and feed only
// discarded output rows. B must be fully padded to 64-row multiples (it is).
__global__ __launch_bounds__(256) void mfma_gemm(
    const ushort* __restrict__ A, const ushort* __restrict__ Bt,
    const float* __restrict__ bias,
    float* __restrict__ Cf, ushort* __restrict__ Cbf, float* __restrict__ gb,
    int M, int N, int K, int kSlice, int mode) {
  int tid = threadIdx.x;
  int lane = tid & 63, wave = tid >> 6;
  int wm = wave >> 1, wn = wave & 1;
  int rowBase = blockIdx.y * 64, colBase = blockIdx.x * 64;
  int m = lane & 15, kg = lane >> 4;
  int kBeg = blockIdx.z * kSlice;
  int kEnd = imin(K, kBeg + kSlice);
  f32x4 acc[2][2] = {};
#ifdef HAVE_GLL
  __shared__ short As[64 * 64];
  __shared__ short Bs[64 * 64];
  // staging lane geometry: 8 rows x 8 chunks(16B) per instruction; swizzle slot=chunk^row
  int r8 = lane >> 3;
  int cs = (lane & 7) ^ r8;            // swizzled source chunk
  const ushort* aG0 = A + (long)(rowBase + wave * 8 + r8) * K + cs * 8 + kBeg;
  const ushort* aG1 = aG0 + (long)32 * K;
  const ushort* bG0 = Bt + (long)(colBase + wave * 8 + r8) * K + cs * 8 + kBeg;
  const ushort* bG1 = bG0 + (long)32 * K;
  short* lA0 = &As[(wave * 8) * 64];
  short* lA1 = &As[(wave * 8 + 32) * 64];
  short* lB0 = &Bs[(wave * 8) * 64];
  short* lB1 = &Bs[(wave * 8 + 32) * 64];
  int xa = m & 7;
  for (int k0 = 0; k0 < kEnd - kBeg; k0 += 64) {
    gll16(aG0 + k0, lA0);
    gll16(aG1 + k0, lA1);
    gll16(bG0 + k0, lB0);
    gll16(bG1 + k0, lB1);
    __syncthreads();
#pragma unroll
    for (int ks = 0; ks < 2; ++ks) {
      int kc = ks * 4 + kg;
      short8 a0 = *(const short8*)&As[(wm * 32 + m) * 64 + (kc ^ xa) * 8];
      short8 a1 = *(const short8*)&As[(wm * 32 + 16 + m) * 64 + (kc ^ xa) * 8];
      short8 b0 = *(const short8*)&Bs[(wn * 32 + m) * 64 + (kc ^ xa) * 8];
      short8 b1 = *(const short8*)&Bs[(wn * 32 + 16 + m) * 64 + (kc ^ xa) * 8];
      acc[0][0] = __builtin_amdgcn_mfma_f32_16x16x32_bf16(a0, b0, acc[0][0], 0, 0, 0);
      acc[0][1] = __builtin_amdgcn_mfma_f32_16x16x32_bf16(a0, b1, acc[0][1], 0, 0, 0);
      acc[1][0] = __builtin_amdgcn_mfma_f32_16x16x32_bf16(a1, b0, acc[1][0], 0, 0, 0);
      acc[1][1] = __builtin_amdgcn_mfma_f32_16x16x32_bf16(a1, b1, acc[1][1], 0, 0, 0);
    }
    __syncthreads();
  }
#else
  __shared__ short As[64][72];
  __shared__ short Bs[64][72];
  for (int k0 = kBeg; k0 < kEnd; k0 += 64) {
#pragma unroll
    for (int cc = 0; cc < 2; ++cc) {
      int c = tid * 2 + cc;
      int r = c >> 3, kc = c & 7;
      short8 av = {};
      int gr = rowBase + r;
      if (gr < M) av = *(const short8*)(A + (long)gr * K + k0 + kc * 8);
      *(short8*)&As[r][kc * 8] = av;
      short8 bv = *(const short8*)(Bt + (long)(colBase + r) * K + k0 + kc * 8);
      *(short8*)&Bs[r][kc * 8] = bv;
    }
    __syncthreads();
#pragma unroll
    for (int ks = 0; ks < 2; ++ks) {
      short8 a0 = *(const short8*)&As[wm * 32 + m][ks * 32 + kg * 8];
      short8 a1 = *(const short8*)&As[wm * 32 + 16 + m][ks * 32 + kg * 8];
      short8 b0 = *(const short8*)&Bs[wn * 32 + m][ks * 32 + kg * 8];
      short8 b1 = *(const short8*)&Bs[wn * 32 + 16 + m][ks * 32 + kg * 8];
      acc[0][0] = __builtin_amdgcn_mfma_f32_16x16x32_bf16(a0, b0, acc[0][0], 0, 0, 0);
      acc[0][1] = __builtin_amdgcn_mfma_f32_16x16x32_bf16(a0, b1, acc[0][1], 0, 0, 0);
      acc[1][0] = __builtin_amdgcn_mfma_f32_16x16x32_bf16(a1, b0, acc[1][0], 0, 0, 0);
      acc[1][1] = __builtin_amdgcn_mfma_f32_16x16x32_bf16(a1, b1, acc[1][1], 0, 0, 0);
    }
    __syncthreads();
  }
#endif
#pragma unroll
  for (int mt = 0; mt < 2; ++mt)
#pragma unroll
    for (int nt = 0; nt < 2; ++nt) {
      int col = colBase + wn * 32 + nt * 16 + m;
#pragma unroll
      for (int r = 0; r < 4; ++r) {
        int row = rowBase + wm * 32 + mt * 16 + kg * 4 + r;
        if (row >= M) continue;
        float v = acc[mt][nt][r];
        if (mode == 2) {
          if (col < QKVN) Cbf[(long)row * QKVN + col] = bf16_rne(v);
          else if (col < QKVNG) gb[(long)row * 64 + (col - QKVN)] = 1.f / (1.f + __expf(-v));
        } else if (mode == 1) {
          v += bias[col];
          float u = 0.7978845608028654f * (v + 0.044715f * v * v * v);
          v = 0.5f * v * (1.f + tanhf(u));
          Cbf[(long)row * N + col] = bf16_rne(v);
        } else {  // mode 4
          if (bias && blockIdx.z == 0) v += bias[col];
          atomicAdd(&Cf[(long)row * N + col], v);
        }
      }
    }
}

// ---------------- ck (z=0) + cv-transposed-into-Vt (z=1), one dispatch ----------------
__global__ __launch_bounds__(256) void ckcv_gemm(
    const ushort* __restrict__ kwm, const ushort* __restrict__ vwm,
    const ushort* __restrict__ wkc_t, const ushort* __restrict__ wvc_t,
    ushort* __restrict__ ckb, ushort* __restrict__ Vt) {
  const int K = 1024;
  bool cvpath = blockIdx.z != 0;
  const ushort* A  = cvpath ? wvc_t : kwm;
  const ushort* Bt = cvpath ? vwm : wkc_t;
  int rowBase = cvpath ? 0 : blockIdx.y * 64;
  int colBase = cvpath ? blockIdx.y * 64 : 0;
  int aRows = cvpath ? 64 : MCKD;
  int bRows = cvpath ? MCKD : 64;
  __shared__ short As[64][72];
  __shared__ short Bs[64][72];
  int tid = threadIdx.x;
  int lane = tid & 63, wave = tid >> 6;
  int wm = wave >> 1, wn = wave & 1;
  int m = lane & 15, kg = lane >> 4;
  f32x4 acc[2][2] = {};
  for (int k0 = 0; k0 < K; k0 += 64) {
#pragma unroll
    for (int cc = 0; cc < 2; ++cc) {
      int c = tid * 2 + cc;
      int r = c >> 3, kc = c & 7;
      short8 av = {};
      if (rowBase + r < aRows) av = *(const short8*)(A + (long)(rowBase + r) * K + k0 + kc * 8);
      *(short8*)&As[r][kc * 8] = av;
      short8 bv = {};
      if (colBase + r < bRows) bv = *(const short8*)(Bt + (long)(colBase + r) * K + k0 + kc * 8);
      *(short8*)&Bs[r][kc * 8] = bv;
    }
    __syncthreads();
#pragma unroll
    for (int ks = 0; ks < 2; ++ks) {
      short8 a0 = *(const short8*)&As[wm * 32 + m][ks * 32 + kg * 8];
      short8 a1 = *(const short8*)&As[wm * 32 + 16 + m][ks * 32 + kg * 8];
      short8 b0 = *(const short8*)&Bs[wn * 32 + m][ks * 32 + kg * 8];
      short8 b1 = *(const short8*)&Bs[wn * 32 + 16 + m][ks * 32 + kg * 8];
      acc[0][0] = __builtin_amdgcn_mfma_f32_16x16x32_bf16(a0, b0, acc[0][0], 0, 0, 0);
      acc[0][1] = __builtin_amdgcn_mfma_f32_16x16x32_bf16(a0, b1, acc[0][1], 0, 0, 0);
      acc[1][0] = __builtin_amdgcn_mfma_f32_16x16x32_bf16(a1, b0, acc[1][0], 0, 0, 0);
      acc[1][1] = __builtin_amdgcn_mfma_f32_16x16x32_bf16(a1, b1, acc[1][1], 0, 0, 0);
    }
    __syncthreads();
  }
#pragma unroll
  for (int mt = 0; mt < 2; ++mt)
#pragma unroll
    for (int nt = 0; nt < 2; ++nt) {
      int col = colBase + wn * 32 + nt * 16 + m;
#pragma unroll
      for (int r = 0; r < 4; ++r) {
        int row = rowBase + wm * 32 + mt * 16 + kg * 4 + r;
        float v = acc[mt][nt][r];
        if (!cvpath) {
          if (row < MCKD) ckb[(long)row * DHD + col] = bf16_rne(v);
        } else {
          if (col < MCKD) {
            int z16 = col / NC, j = col - z16 * NC;
            Vt[((long)z16 * 64 + row) * PSTRIDE + 640 + j] = bf16_rne(v);
          }
        }
      }
    }
}

// ---------------- batched score GEMM: merged dense (x<10) + compressed (x>=10) ----------------
__global__ __launch_bounds__(256) void score_kernel(
    const ushort* __restrict__ qkv_bf, const ushort* __restrict__ ckb,
    ushort* __restrict__ Sf, ushort* __restrict__ Scb, float scale) {
  __shared__ short As[64][72];
  __shared__ short Bs[64][72];
  int z = blockIdx.z;
  int b = z >> 3, h = z & 7;
  int i0 = blockIdx.y * 64;
  int xb = blockIdx.x;
  bool isC = xb >= 10;
  int j0 = (isC ? (xb - 10) : xb) * 64;
  int tid = threadIdx.x;
  int lane = tid & 63, wave = tid >> 6;
  int wm = wave >> 1, wn = wave & 1;
  const ushort* aBase = qkv_bf + (long)b * NTOK * QKVN + h * 64;
  const ushort* bBase = aBase + 512;
  const ushort* cBase = ckb + (long)z * NC * DHD;
#pragma unroll
  for (int rep = 0; rep < 4; ++rep) {
    int row = rep * 16 + (tid >> 4);
    int c4 = tid & 15;
    int gi = i0 + row;
    short4v a16 = {};
    if (gi < NTOK) a16 = *(const short4v*)(aBase + (long)gi * QKVN + c4 * 4);
    *(short4v*)&As[row][c4 * 4] = a16;
    int gj = j0 + row;
    short4v b16 = {};
    if (isC) {
      if (gj < NC) b16 = *(const short4v*)(cBase + (long)gj * DHD + c4 * 4);
    } else {
      if (gj < NTOK) b16 = *(const short4v*)(bBase + (long)gj * QKVN + c4 * 4);
    }
    *(short4v*)&Bs[row][c4 * 4] = b16;
  }
  __syncthreads();
  int m = lane & 15, kg = lane >> 4;
  f32x4 acc[2][2] = {};
#pragma unroll
  for (int ks = 0; ks < 2; ++ks) {
    short8 a0 = *(const short8*)&As[wm * 32 + m][ks * 32 + kg * 8];
    short8 a1 = *(const short8*)&As[wm * 32 + 16 + m][ks * 32 + kg * 8];
    short8 b0 = *(const short8*)&Bs[wn * 32 + m][ks * 32 + kg * 8];
    short8 b1 = *(const short8*)&Bs[wn * 32 + 16 + m][ks * 32 + kg * 8];
    acc[0][0] = __builtin_amdgcn_mfma_f32_16x16x32_bf16(a0, b0, acc[0][0], 0, 0, 0);
    acc[0][1] = __builtin_amdgcn_mfma_f32_16x16x32_bf16(a0, b1, acc[0][1], 0, 0, 0);
    acc[1][0] = __builtin_amdgcn_mfma_f32_16x16x32_bf16(a1, b0, acc[1][0], 0, 0, 0);
    acc[1][1] = __builtin_amdgcn_mfma_f32_16x16x32_bf16(a1, b1, acc[1][1], 0, 0, 0);
  }
  int nvalid = isC ? NC : NTOK;
  int sstride = isC ? SCSTRIDE : SFSTRIDE;
  ushort* Sz = (isC ? Scb : Sf) + (long)z * NTOK * sstride;
#pragma unroll
  for (int mt = 0; mt < 2; ++mt)
#pragma unroll
    for (int nt = 0; nt < 2; ++nt) {
      int col = j0 + wn * 32 + nt * 16 + m;
#pragma unroll
      for (int r = 0; r < 4; ++r) {
        int row = i0 + wm * 32 + mt * 16 + kg * 4 + r;
        if (row < NTOK && col < nvalid)
          Sz[(long)row * sstride + col] = bf16_rne(acc[mt][nt][r] * scale);
      }
    }
}

// ---------------- kw/vw build + Vt V-part (merged; block-range decode) ----------------
__global__ void kwvt_kernel(const ushort* __restrict__ qkv_bf,
                            const float* __restrict__ kpe, const float* __restrict__ vpe,
                            ushort* __restrict__ kwm, ushort* __restrict__ vwm,
                            ushort* __restrict__ Vt) {
  __shared__ short tile[64][72];
  int bid = blockIdx.x;
  if (bid < MCKD) {
    int j = bid % NC;
    int bh = bid / NC;
    int h = bh & 7, b = bh >> 3;
    int t = threadIdx.x >> 4;
    int d4 = threadIdx.x & 15;
    int tok = j * CSD + t;
    float k0 = 0.f, k1 = 0.f, k2 = 0.f, k3 = 0.f, v0 = 0.f, v1 = 0.f, v2 = 0.f, v3 = 0.f;
    if (tok < NTOK) {
      const ushort* base = qkv_bf + (long)(b * NTOK + tok) * QKVN + h * DHD + d4 * 4;
      short4v kv = *(const short4v*)(base + 512);
      short4v vv = *(const short4v*)(base + 1024);
      k0 = bf16_to_f((ushort)kv.x); k1 = bf16_to_f((ushort)kv.y);
      k2 = bf16_to_f((ushort)kv.z); k3 = bf16_to_f((ushort)kv.w);
      v0 = bf16_to_f((ushort)vv.x); v1 = bf16_to_f((ushort)vv.y);
      v2 = bf16_to_f((ushort)vv.z); v3 = bf16_to_f((ushort)vv.w);
    }
    float4 kp = *(const float4*)(kpe + t * DHD + d4 * 4);
    float4 vp = *(const float4*)(vpe + t * DHD + d4 * 4);
    short4v ko, vo;
    ko.x = (short)bf16_rne(k0 + kp.x); ko.y = (short)bf16_rne(k1 + kp.y);
    ko.z = (short)bf16_rne(k2 + kp.z); ko.w = (short)bf16_rne(k3 + kp.w);
    vo.x = (short)bf16_rne(v0 + vp.x); vo.y = (short)bf16_rne(v1 + vp.y);
    vo.z = (short)bf16_rne(v2 + vp.z); vo.w = (short)bf16_rne(v3 + vp.w);
    long ob = (long)bid * 1024 + t * DHD + d4 * 4;
    *(short4v*)(kwm + ob) = ko;
    *(short4v*)(vwm + ob) = vo;
  } else {
    int t = bid - MCKD;      // 0..159
    int kt = t % 10, z = t / 10;
    int b = z >> 3, h = z & 7;
    int tid = threadIdx.x;
    int r = tid >> 2, seg = tid & 3;
    short8 a0 = {}, a1 = {};
    int tok = kt * 64 + r;
    if (tok < NTOK) {
      const ushort* src = qkv_bf + (long)(b * NTOK + tok) * QKVN + 1024 + h * 64 + seg * 16;
      a0 = *(const short8*)src;
      a1 = *(const short8*)(src + 8);
    }
    *(short8*)&tile[r][seg * 16] = a0;
    *(short8*)&tile[r][seg * 16 + 8] = a1;
    __syncthreads();
    int d = tid >> 2;
    short8 o0, o1;
#pragma unroll
    for (int q = 0; q < 8; ++q) o0[q] = tile[seg * 16 + q][d];
#pragma unroll
    for (int q = 0; q < 8; ++q) o1[q] = tile[seg * 16 + 8 + q][d];
    ushort* dst = Vt + ((long)z * 64 + d) * PSTRIDE + kt * 64 + seg * 16;
    *(short8*)dst = o0;
    *(short8*)(dst + 8) = o1;
  }
}

// ---------------- prob: softmax + top-k + gates -> dense gated P row ----------------
__global__ __launch_bounds__(256, 4) void prob_kernel(
    const ushort* __restrict__ Sf, const ushort* __restrict__ Scb,
    const float* __restrict__ gb, ushort* __restrict__ P) {
  int qt = blockIdx.x % NC;
  int z = blockIdx.x / NC;
  int h = z & 7, b = z >> 3;
  int tid = threadIdx.x, lane = tid & 63, w = tid >> 6;
  int i0 = qt * 4 + w;
  bool valid = i0 < NTOK;
  int i = imin(i0, NTOK - 1);

  __shared__ float scL[4][192];
  __shared__ float ssL[4][256];
  __shared__ float swL[4][32];
  __shared__ float impL[4][16];
  __shared__ int selL[4][KSELD];
  float* sc = scL[w]; float* ss = ssL[w];
  float* swv = swL[w]; float* imp = impL[w]; int* sel = selL[w];

  const ushort* scRow = Scb + ((long)z * NTOK + i) * SCSTRIDE;
  const ushort* sfRow = Sf + ((long)z * NTOK + i) * SFSTRIDE;

  float e[3], mC = -1e30f;
#pragma unroll
  for (int c = 0; c < 3; ++c) {
    int j = c * 64 + lane;
    float s = bf16_to_f(scRow[imin(j, NC - 1)]);
    s = (j < NC) ? s : -1e30f;
    e[c] = s;
    mC = fmaxf(mC, s);
  }
#pragma unroll
  for (int msk = 1; msk < 64; msk <<= 1) mC = fmaxf(mC, __shfl_xor(mC, msk, 64));
  float sumC = 0.f;
#pragma unroll
  for (int c = 0; c < 3; ++c) {
    float ev = (e[c] > -1e29f) ? __expf(e[c] - mC) : 0.f;
    sc[c * 64 + lane] = ev;
    sumC += ev;
  }
#pragma unroll
  for (int msk = 1; msk < 64; msk <<= 1) sumC += __shfl_xor(sumC, msk, 64);
  __syncthreads();

  if (lane < NSB) {
    int lo = imax(0, 16 * lane - 2), hi = imin(NC - 1, 16 * lane + 13);
    float s = 0.f;
    for (int j = lo; j <= hi; ++j) s += sc[j];
    imp[lane] = s;
  }
  __syncthreads();
  if (lane == 0) {
    unsigned used = 0;
    for (int r = 0; r < KSELD; ++r) {
      int bi = 0; float bv = -1e30f;
      for (int s = 0; s < NSB; ++s)
        if (!((used >> s) & 1u) && imp[s] > bv) { bv = imp[s]; bi = s; }
      used |= 1u << bi;
      sel[r] = bi;
    }
  }
  __syncthreads();

  float es[4], mS = -1e30f;
#pragma unroll
  for (int c = 0; c < 4; ++c) {
    int tok = sel[c] * SBD + lane;
    float s = bf16_to_f(sfRow[imin(tok, NTOK - 1)]);
    s = (tok < NTOK) ? s : -1e30f;
    es[c] = s;
    mS = fmaxf(mS, s);
  }
#pragma unroll
  for (int msk = 1; msk < 64; msk <<= 1) mS = fmaxf(mS, __shfl_xor(mS, msk, 64));
  float sumS = 0.f;
#pragma unroll
  for (int c = 0; c < 4; ++c) {
    float ev = (es[c] > -1e29f) ? __expf(es[c] - mS) : 0.f;
    ss[c * 64 + lane] = ev;
    sumS += ev;
  }
#pragma unroll
  for (int msk = 1; msk < 64; msk <<= 1) sumS += __shfl_xor(sumS, msk, 64);

  float sw_s;
  {
    int pos = i + (lane & 31) - SWD / 2;
    float s = bf16_to_f(sfRow[imin(imax(pos, 0), NTOK - 1)]);
    sw_s = (pos >= 0 && pos < NTOK) ? s : -1e30f;
  }
  float mW = sw_s;
#pragma unroll
  for (int msk = 1; msk < 32; msk <<= 1) mW = fmaxf(mW, __shfl_xor(mW, msk, 64));
  float ew = (sw_s > -1e29f) ? __expf(sw_s - mW) : 0.f;
  float sumW = ew;
#pragma unroll
  for (int msk = 1; msk < 32; msk <<= 1) sumW += __shfl_xor(sumW, msk, 64);
  if (lane < SWD) swv[lane] = ew;
  __syncthreads();

  if (!valid) return;
  const float* gp = gb + (long)(b * NTOK + i) * 64 + h * 3;
  float rC = gp[0] / sumC, rS = gp[1] / sumS, rW = gp[2] / sumW;
  ushort* prow = P + ((long)z * NTOK + i0) * PSTRIDE;
#pragma unroll
  for (int c = 0; c < 10; ++c) {
    int col = c * 64 + lane;
    float val = 0.f;
#pragma unroll
    for (int r = 0; r < 4; ++r)
      if (sel[r] == c) val += rS * ss[r * 64 + lane];
    int t = col - i + 16;
    if (t >= 0 && t < SWD && col < NTOK) val += rW * swv[t];
    prow[col] = bf16_rne(val);
  }
#pragma unroll
  for (int c = 0; c < 3; ++c) {
    int j = c * 64 + lane;
    float val = (j < NC) ? rC * sc[j] : 0.f;
    prow[640 + j] = bf16_rne(val);
  }
}

// ---------------- PV GEMM: comb[b,i,h*64+d] = P[z] @ Vext[z] ----------------
__global__ __launch_bounds__(256) void pv_gemm(const ushort* __restrict__ P,
                                               const ushort* __restrict__ Vt,
                                               ushort* __restrict__ comb) {
  __shared__ short As[64][72];
  __shared__ short Bs[64][72];
  int z = blockIdx.y;
  int b = z >> 3, h = z & 7;
  int rowBase = blockIdx.x * 64;
  int tid = threadIdx.x;
  int lane = tid & 63, wave = tid >> 6;
  int wm = wave >> 1, wn = wave & 1;
  const ushort* Pz = P + (long)z * NTOK * PSTRIDE;
  const ushort* Vz = Vt + (long)z * 64 * PSTRIDE;
  int m = lane & 15, kg = lane >> 4;
  f32x4 acc[2][2] = {};
  for (int k0 = 0; k0 < PSTRIDE; k0 += 64) {
#pragma unroll
    for (int cc = 0; cc < 2; ++cc) {
      int c = tid * 2 + cc;
      int r = c >> 3, kc = c & 7;
      short8 av = {};
      int gr = rowBase + r;
      if (gr < NTOK) av = *(const short8*)(Pz + (long)gr * PSTRIDE + k0 + kc * 8);
      *(short8*)&As[r][kc * 8] = av;
      short8 bv = *(const short8*)(Vz + (long)r * PSTRIDE + k0 + kc * 8);
      *(short8*)&Bs[r][kc * 8] = bv;
    }
    __syncthreads();
#pragma unroll
    for (int ks = 0; ks < 2; ++ks) {
      short8 a0 = *(const short8*)&As[wm * 32 + m][ks * 32 + kg * 8];
      short8 a1 = *(const short8*)&As[wm * 32 + 16 + m][ks * 32 + kg * 8];
      short8 b0 = *(const short8*)&Bs[wn * 32 + m][ks * 32 + kg * 8];
      short8 b1 = *(const short8*)&Bs[wn * 32 + 16 + m][ks * 32 + kg * 8];
      acc[0][0] = __builtin_amdgcn_mfma_f32_16x16x32_bf16(a0, b0, acc[0][0], 0, 0, 0);
      acc[0][1] = __builtin_amdgcn_mfma_f32_16x16x32_bf16(a0, b1, acc[0][1], 0, 0, 0);
      acc[1][0] = __builtin_amdgcn_mfma_f32_16x16x32_bf16(a1, b0, acc[1][0], 0, 0, 0);
      acc[1][1] = __builtin_amdgcn_mfma_f32_16x16x32_bf16(a1, b1, acc[1][1], 0, 0, 0);
    }
    __syncthreads();
  }
#pragma unroll
  for (int mt = 0; mt < 2; ++mt)
#pragma unroll
    for (int nt = 0; nt < 2; ++nt) {
      int col = wn * 32 + nt * 16 + m;
#pragma unroll
      for (int r = 0; r < 4; ++r) {
        int row = rowBase + wm * 32 + mt * 16 + kg * 4 + r;
        if (row < NTOK)
          comb[(long)(b * NTOK + row) * DIMD + h * 64 + col] = bf16_rne(acc[mt][nt][r]);
      }
    }
}

// ---------------- head with fused final LN ----------------
__global__ void head_kernel(const float* __restrict__ x, const float* __restrict__ hg,
                            const float* __restrict__ hb, const float* __restrict__ W,
                            const float* __restrict__ bias, float* __restrict__ out) {
  int b = blockIdx.y;
  int tid = threadIdx.x;
  const float* xr = x + (long)b * NTOK * DIMD;
  __shared__ float red1[256], red2[256];
  float a = xr[tid], c = xr[tid + 256];
  red1[tid] = a + c;
  red2[tid] = a * a + c * c;
  __syncthreads();
  for (int off = 128; off > 0; off >>= 1) {
    if (tid < off) { red1[tid] += red1[tid + off]; red2[tid] += red2[tid + off]; }
    __syncthreads();
  }
  float m = red1[0] * (1.f / 512.f);
  float var = red2[0] * (1.f / 512.f) - m * m;
  float rs = rsqrtf(var + 1e-5f);
  __shared__ float hs[512];
  hs[tid] = (a - m) * rs * hg[tid] + hb[tid];
  hs[tid + 256] = (c - m) * rs * hg[tid + 256] + hb[tid + 256];
  __syncthreads();
  int col = blockIdx.x * 64 + (tid & 63);
  int ks = tid >> 6;
  float acc = 0.f;
  if (col < NCLSD) {
    for (int k = ks * 128; k < ks * 128 + 128; ++k)
      acc += hs[k] * W[(long)k * NCLSD + col];
  }
  __shared__ float part[4][64];
  part[ks][tid & 63] = acc;
  __syncthreads();
  if (tid < 64) {
    int c2 = blockIdx.x * 64 + tid;
    if (c2 < NCLSD)
      out[b * NCLSD + c2] = part[0][tid] + part[1][tid] + part[2][tid] + part[3][tid] + bias[c2];
  }
}

extern "C" void kernel_launch(void* const* d_in, const int* in_sizes, int n_in,
                              void* d_out, int out_size, void* d_ws, size_t ws_size,
                              hipStream_t stream) {
  const float* img     = (const float*)d_in[0];
  const float* patch_w = (const float*)d_in[1];
  const float* patch_b = (const float*)d_in[2];
  const float* pos_emb = (const float*)d_in[3];
  const float* cls_tok = (const float*)d_in[4];
  const float* ln1_g   = (const float*)d_in[5];
  const float* ln1_b   = (const float*)d_in[6];
  const float* Wq      = (const float*)d_in[7];
  const float* Wk      = (const float*)d_in[8];
  const float* Wv      = (const float*)d_in[9];
  const float* Wg      = (const float*)d_in[10];
  const float* Wo      = (const float*)d_in[11];
  const float* kpe     = (const float*)d_in[12];
  const float* vpe     = (const float*)d_in[13];
  const float* Wkc     = (const float*)d_in[14];
  const float* Wvc     = (const float*)d_in[15];
  const float* ln2_g   = (const float*)d_in[16];
  const float* ln2_b   = (const float*)d_in[17];
  const float* ff_w1   = (const float*)d_in[18];
  const float* ff_b1   = (const float*)d_in[19];
  const float* ff_w2   = (const float*)d_in[20];
  const float* ff_b2   = (const float*)d_in[21];
  const float* hln_g   = (const float*)d_in[22];
  const float* hln_b   = (const float*)d_in[23];
  const float* head_w  = (const float*)d_in[24];
  const float* head_b  = (const float*)d_in[25];
  float* out = (float*)d_out;

  // ---- workspace carve (~54 MB; ws is 256 MB). NOTE: mfma_gemm GLL staging may
  // read up to 64 rows past an A buffer's end — all A buffers are ws-interior. ----
  char* p = (char*)d_ws;
  const long MROW = (long)BATCH * NTOK;            // 1154
  float* x       = (float*)p;  p += MROW * DIMD * 4;
  ushort* qkv_bf = (ushort*)p; p += MROW * QKVN * 2;
  ushort* h_bf   = (ushort*)p; p += MROW * DIMD * 2;
  ushort* comb_bf= (ushort*)p; p += MROW * DIMD * 2;
  float* gb      = (float*)p;  p += MROW * 64 * 4;
  ushort* ckb    = (ushort*)p; p += (long)MCKD * DHD * 2;
  ushort* Vt     = (ushort*)p; p += (long)BATCH * NH * 64 * PSTRIDE * 2;
  ushort* Scb    = (ushort*)p; p += (long)BATCH * NH * NTOK * SCSTRIDE * 2;
  ushort* wqkv_t = (ushort*)p; p += 2L * QKVNG * DIMD * 2;
  ushort* wo_t   = (ushort*)p; p += 2L * DIMD * DIMD * 2;
  ushort* w1_t   = (ushort*)p; p += 2L * MLPD * DIMD * 2;
  ushort* w2_t   = (ushort*)p; p += 2L * DIMD * MLPD * 2;
  ushort* wkc_t  = (ushort*)p; p += 2L * 64 * 1024 * 2;
  ushort* wvc_t  = (ushort*)p; p += 2L * 64 * 1024 * 2;
  ushort* kwm    = (ushort*)p;
  ushort* vwm    = kwm + (long)MCKD * 1024;
  ushort* P      = kwm;
  p += (long)BATCH * NH * NTOK * PSTRIDE * 2;
  ushort* Sf     = (ushort*)p;
  ushort* ff1_bf = Sf;
  p += (long)BATCH * NH * NTOK * SFSTRIDE * 2;
  p += 64 * 2048 * 2;  // tail slack so GLL OOB A-tile reads stay in-bounds

  const int M = (int)MROW;                  // 1154
  const int MB64 = (M + 63) / 64;           // 19
  const float scale = 0.125f;

  // merged: both layers' weight transposes + patch embed, one dispatch
  prep_kernel<<<6464 + (int)((M * DIMD + 255) / 256), 256, 0, stream>>>(
      Wq, Wk, Wv, Wg, Wo, Wkc, Wvc, ff_w1, ff_w2,
      wqkv_t, wo_t, w1_t, w2_t, wkc_t, wvc_t,
      img, patch_w, patch_b, pos_emb, cls_tok, x);

  for (int l = 0; l < 2; ++l) {
    const ushort* wqkv_l = wqkv_t + (long)l * QKVNG * DIMD;
    const ushort* wo_l   = wo_t + (long)l * DIMD * DIMD;
    const ushort* w1t_l  = w1_t + (long)l * MLPD * DIMD;
    const ushort* w2t_l  = w2_t + (long)l * DIMD * MLPD;
    const ushort* wkc_l  = wkc_t + (long)l * 64 * 1024;
    const ushort* wvc_l  = wvc_t + (long)l * 64 * 1024;
    const float* kpe_l = kpe + (long)l * CBD * DHD;
    const float* vpe_l = vpe + (long)l * CBD * DHD;
    const float* b1_l  = ff_b1 + (long)l * MLPD;
    const float* b2_l  = ff_b2 + (long)l * DIMD;

    ln_kernel<<<M, 256, 0, stream>>>(x, ln1_g + (long)l * DIMD, ln1_b + (long)l * DIMD, h_bf);
    mfma_gemm<<<dim3(QKVNG / 64, MB64), 256, 0, stream>>>(h_bf, wqkv_l, nullptr, nullptr, qkv_bf, gb, M, QKVNG, DIMD, DIMD, 2);
    kwvt_kernel<<<MCKD + 160, 256, 0, stream>>>(qkv_bf, kpe_l, vpe_l, kwm, vwm, Vt);
    ckcv_gemm<<<dim3(1, (MCKD + 63) / 64, 2), 256, 0, stream>>>(kwm, vwm, wkc_l, wvc_l, ckb, Vt);
    score_kernel<<<dim3(13, 10, BATCH * NH), 256, 0, stream>>>(qkv_bf, ckb, Sf, Scb, scale);
    prob_kernel<<<BATCH * NH * NC, 256, 0, stream>>>(Sf, Scb, gb, P);
    pv_gemm<<<dim3(10, BATCH * NH), 256, 0, stream>>>(P, Vt, comb_bf);
    mfma_gemm<<<dim3(DIMD / 64, MB64, 2), 256, 0, stream>>>(comb_bf, wo_l, nullptr, x, nullptr, nullptr, M, DIMD, DIMD, 256, 4);
    ln_kernel<<<M, 256, 0, stream>>>(x, ln2_g + (long)l * DIMD, ln2_b + (long)l * DIMD, h_bf);
    mfma_gemm<<<dim3(MLPD / 64, MB64), 256, 0, stream>>>(h_bf, w1t_l, b1_l, nullptr, ff1_bf, nullptr, M, MLPD, DIMD, DIMD, 1);
    mfma_gemm<<<dim3(DIMD / 64, MB64, 4), 256, 0, stream>>>(ff1_bf, w2t_l, b2_l, x, nullptr, nullptr, M, DIMD, MLPD, 512, 4);
  }

  head_kernel<<<dim3(16, BATCH), 256, 0, stream>>>(x, hln_g, hln_b, head_w, head_b, out);
}